// Round 1
// baseline (377.014 us; speedup 1.0000x reference)
//
#include <hip/hip_runtime.h>
#include <hip/hip_bf16.h>
#include <math.h>

#define B_   16
#define N_   4096
#define D_   768
#define H_   12
#define L_   2
#define K_   16
#define S_   17
#define M_   272          // B_*S_
#define BN_  65536        // B_*N_

// ---------------------------------------------------------------------------
// Kernel 0: A1[e] = sum_d gln_g[d]*gW1[e,d];  A2[e] = sum_d gln_b[d]*gW1[e,d]
// ---------------------------------------------------------------------------
__global__ void precompute_kernel(const float* __restrict__ gW1,
                                  const float* __restrict__ gln_g,
                                  const float* __restrict__ gln_b,
                                  float* __restrict__ A1, float* __restrict__ A2)
{
    int e = threadIdx.x;   // 64 threads
    float a1 = 0.f, a2 = 0.f;
    for (int d = 0; d < D_; ++d) {
        float w = gW1[(size_t)e * D_ + d];
        a1 = fmaf(gln_g[d], w, a1);
        a2 = fmaf(gln_b[d], w, a2);
    }
    A1[e] = a1; A2[e] = a2;
}

// ---------------------------------------------------------------------------
// Kernel 1: fused gate.  Per block: 64 instances.
//   S1[inst][e] = sum_d x[inst][d] * (gln_g[d]*gW1[e][d])   (GEMM, LDS tiled)
//   stats (sum, sumsq) accumulated during staging
//   h = rstd*(S1 - m*A1) + A2 + gb1 ; gelu ; t = sum_e gelu*gW2 ; w = sigmoid
// ---------------------------------------------------------------------------
__global__ __launch_bounds__(256)
void gate_kernel(const float* __restrict__ x,
                 const float* __restrict__ gln_g,
                 const float* __restrict__ gW1,
                 const float* __restrict__ gb1,
                 const float* __restrict__ gW2,
                 const float* __restrict__ gb2,
                 const float* __restrict__ A1,
                 const float* __restrict__ A2,
                 float* __restrict__ wbuf)
{
    __shared__ float Xs[64 * 68];
    __shared__ float Ws[64 * 68];
    __shared__ float red[2][16][64];
    __shared__ float m_s[64], r_s[64];

    const int tid = threadIdx.x;
    const int ty  = tid >> 4;        // 0..15
    const int tx  = tid & 15;        // 0..15
    const int bn0 = blockIdx.x * 64;

    float acc[4][4] = {};
    float sxp[4] = {}, sxxp[4] = {};

    const int cc = tx * 4;

    for (int kt = 0; kt < 12; ++kt) {
        __syncthreads();
        #pragma unroll
        for (int p = 0; p < 4; ++p) {
            int r = ty + p * 16;
            float4 xv = *(const float4*)&x[(size_t)(bn0 + r) * D_ + kt * 64 + cc];
            Xs[r * 68 + cc + 0] = xv.x;
            Xs[r * 68 + cc + 1] = xv.y;
            Xs[r * 68 + cc + 2] = xv.z;
            Xs[r * 68 + cc + 3] = xv.w;
            sxp[p]  += xv.x + xv.y + xv.z + xv.w;
            sxxp[p] += xv.x * xv.x + xv.y * xv.y + xv.z * xv.z + xv.w * xv.w;
            float4 wv = *(const float4*)&gW1[(size_t)r * D_ + kt * 64 + cc];
            float4 gv = *(const float4*)&gln_g[kt * 64 + cc];
            Ws[r * 68 + cc + 0] = wv.x * gv.x;
            Ws[r * 68 + cc + 1] = wv.y * gv.y;
            Ws[r * 68 + cc + 2] = wv.z * gv.z;
            Ws[r * 68 + cc + 3] = wv.w * gv.w;
        }
        __syncthreads();
        #pragma unroll
        for (int d4 = 0; d4 < 16; ++d4) {
            int d = d4 * 4;
            float4 xf[4], wf[4];
            #pragma unroll
            for (int ii = 0; ii < 4; ++ii) xf[ii] = *(float4*)&Xs[(ty + 16 * ii) * 68 + d];
            #pragma unroll
            for (int jj = 0; jj < 4; ++jj) wf[jj] = *(float4*)&Ws[(tx + 16 * jj) * 68 + d];
            #pragma unroll
            for (int ii = 0; ii < 4; ++ii)
                #pragma unroll
                for (int jj = 0; jj < 4; ++jj) {
                    acc[ii][jj] = fmaf(xf[ii].x, wf[jj].x, acc[ii][jj]);
                    acc[ii][jj] = fmaf(xf[ii].y, wf[jj].y, acc[ii][jj]);
                    acc[ii][jj] = fmaf(xf[ii].z, wf[jj].z, acc[ii][jj]);
                    acc[ii][jj] = fmaf(xf[ii].w, wf[jj].w, acc[ii][jj]);
                }
        }
    }
    __syncthreads();
    #pragma unroll
    for (int p = 0; p < 4; ++p) {
        red[0][tx][ty + 16 * p] = sxp[p];
        red[1][tx][ty + 16 * p] = sxxp[p];
    }
    __syncthreads();
    if (tid < 64) {
        float s = 0.f, ss = 0.f;
        #pragma unroll
        for (int cg = 0; cg < 16; ++cg) { s += red[0][cg][tid]; ss += red[1][cg][tid]; }
        float m   = s * (1.0f / D_);
        float var = ss * (1.0f / D_) - m * m;
        m_s[tid] = m;
        r_s[tid] = rsqrtf(var + 1e-5f);
    }
    __syncthreads();

    float a1v[4], a2v[4], b1v[4], w2v[4];
    #pragma unroll
    for (int jj = 0; jj < 4; ++jj) {
        int e = tx + 16 * jj;
        a1v[jj] = A1[e]; a2v[jj] = A2[e]; b1v[jj] = gb1[e]; w2v[jj] = gW2[e];
    }
    float gb2v = gb2[0];

    #pragma unroll
    for (int ii = 0; ii < 4; ++ii) {
        int inst = ty + 16 * ii;
        float m = m_s[inst], rs = r_s[inst];
        float tp = 0.f;
        #pragma unroll
        for (int jj = 0; jj < 4; ++jj) {
            float h  = rs * (acc[ii][jj] - m * a1v[jj]) + a2v[jj] + b1v[jj];
            float hg = 0.5f * h * (1.0f + erff(h * 0.70710678118654752f));
            tp = fmaf(hg, w2v[jj], tp);
        }
        #pragma unroll
        for (int o = 8; o; o >>= 1) tp += __shfl_xor(tp, o);
        if (tx == 0) wbuf[bn0 + inst] = 1.0f / (1.0f + expf(-(tp + gb2v)));
    }
}

// ---------------------------------------------------------------------------
// Kernel 2: per-bag top-16 (descending, ties -> lower index, like lax.top_k)
// ---------------------------------------------------------------------------
__global__ __launch_bounds__(256)
void topk_kernel(const float* __restrict__ wbuf,
                 float* __restrict__ topv, int* __restrict__ topi)
{
    __shared__ float wsm[N_];
    __shared__ float rv[256];
    __shared__ int   ri[256];
    const int b = blockIdx.x, tid = threadIdx.x;
    for (int i = tid; i < N_; i += 256) wsm[i] = wbuf[(size_t)b * N_ + i];
    __syncthreads();
    for (int k = 0; k < K_; ++k) {
        float bv = -1e30f; int bi = 0x7fffffff;
        for (int i = tid; i < N_; i += 256) {
            float v = wsm[i];
            if (v > bv || (v == bv && i < bi)) { bv = v; bi = i; }
        }
        rv[tid] = bv; ri[tid] = bi;
        __syncthreads();
        for (int s2 = 128; s2 > 0; s2 >>= 1) {
            if (tid < s2) {
                float ov = rv[tid + s2]; int oi = ri[tid + s2];
                if (ov > rv[tid] || (ov == rv[tid] && oi < ri[tid])) { rv[tid] = ov; ri[tid] = oi; }
            }
            __syncthreads();
        }
        if (tid == 0) {
            topv[b * K_ + k] = rv[0];
            topi[b * K_ + k] = ri[0];
            wsm[ri[0]] = -1e30f;
        }
        __syncthreads();
    }
}

// ---------------------------------------------------------------------------
// Kernel 3: build seq = [cls, x[topi]*topv], LayerNorm -> z0, a = z0
// ---------------------------------------------------------------------------
__global__ __launch_bounds__(256)
void build_kernel(const float* __restrict__ x, const float* __restrict__ cls,
                  const float* __restrict__ ln_g, const float* __restrict__ ln_b,
                  const float* __restrict__ topv, const int* __restrict__ topi,
                  float* __restrict__ z0, float* __restrict__ abuf)
{
    const int r = blockIdx.x, b = r / S_, s = r % S_;
    __shared__ float sm[8];
    float v[3];
    if (s == 0) {
        #pragma unroll
        for (int p = 0; p < 3; ++p) v[p] = cls[threadIdx.x + 256 * p];
    } else {
        int   idx = topi[b * K_ + s - 1];
        float tv  = topv[b * K_ + s - 1];
        const float* row = &x[((size_t)b * N_ + idx) * D_];
        #pragma unroll
        for (int p = 0; p < 3; ++p) v[p] = row[threadIdx.x + 256 * p] * tv;
    }
    float sum = 0.f, ss = 0.f;
    #pragma unroll
    for (int p = 0; p < 3; ++p) { sum += v[p]; ss += v[p] * v[p]; }
    #pragma unroll
    for (int o = 32; o; o >>= 1) { sum += __shfl_down(sum, o); ss += __shfl_down(ss, o); }
    int wid = threadIdx.x >> 6, lane = threadIdx.x & 63;
    if (lane == 0) { sm[wid * 2] = sum; sm[wid * 2 + 1] = ss; }
    __syncthreads();
    sum = sm[0] + sm[2] + sm[4] + sm[6];
    ss  = sm[1] + sm[3] + sm[5] + sm[7];
    float m = sum * (1.0f / D_), rstd = rsqrtf(ss * (1.0f / D_) - m * m + 1e-5f);
    #pragma unroll
    for (int p = 0; p < 3; ++p) {
        int d = threadIdx.x + 256 * p;
        float z = (v[p] - m) * rstd * ln_g[d] + ln_b[d];
        z0[(size_t)r * D_ + d]   = z;
        abuf[(size_t)r * D_ + d] = z;
    }
}

// ---------------------------------------------------------------------------
// GEMM: C[m][n] = sum_k A[m][k]*W[n][k] + bias[n] ; M=272, K=768, N param
// tile 32x64, 256 threads, 2x4 per-thread
// ---------------------------------------------------------------------------
__global__ __launch_bounds__(256)
void gemm_kernel(const float* __restrict__ A, const float* __restrict__ W,
                 const float* __restrict__ bias, float* __restrict__ C, int N)
{
    __shared__ float As[32 * 68];
    __shared__ float Ws2[64 * 68];
    const int tid = threadIdx.x;
    const int ty = tid >> 4, tx = tid & 15;
    const int m0 = blockIdx.x * 32, n0 = blockIdx.y * 64;
    const int cc = tx * 4;
    float acc[2][4] = {};

    for (int kt = 0; kt < 12; ++kt) {
        __syncthreads();
        #pragma unroll
        for (int p = 0; p < 2; ++p) {
            int r = ty + p * 16, m = m0 + r;
            float4 av = (m < M_) ? *(const float4*)&A[(size_t)m * D_ + kt * 64 + cc]
                                 : make_float4(0.f, 0.f, 0.f, 0.f);
            As[r * 68 + cc + 0] = av.x; As[r * 68 + cc + 1] = av.y;
            As[r * 68 + cc + 2] = av.z; As[r * 68 + cc + 3] = av.w;
        }
        #pragma unroll
        for (int p = 0; p < 4; ++p) {
            int r = ty + p * 16;
            float4 wv = *(const float4*)&W[(size_t)(n0 + r) * D_ + kt * 64 + cc];
            Ws2[r * 68 + cc + 0] = wv.x; Ws2[r * 68 + cc + 1] = wv.y;
            Ws2[r * 68 + cc + 2] = wv.z; Ws2[r * 68 + cc + 3] = wv.w;
        }
        __syncthreads();
        #pragma unroll
        for (int d4 = 0; d4 < 16; ++d4) {
            int d = d4 * 4;
            float4 a0 = *(float4*)&As[ty * 68 + d];
            float4 a1 = *(float4*)&As[(ty + 16) * 68 + d];
            #pragma unroll
            for (int jj = 0; jj < 4; ++jj) {
                float4 wf = *(float4*)&Ws2[(tx + 16 * jj) * 68 + d];
                acc[0][jj] = fmaf(a0.x, wf.x, acc[0][jj]);
                acc[0][jj] = fmaf(a0.y, wf.y, acc[0][jj]);
                acc[0][jj] = fmaf(a0.z, wf.z, acc[0][jj]);
                acc[0][jj] = fmaf(a0.w, wf.w, acc[0][jj]);
                acc[1][jj] = fmaf(a1.x, wf.x, acc[1][jj]);
                acc[1][jj] = fmaf(a1.y, wf.y, acc[1][jj]);
                acc[1][jj] = fmaf(a1.z, wf.z, acc[1][jj]);
                acc[1][jj] = fmaf(a1.w, wf.w, acc[1][jj]);
            }
        }
    }
    #pragma unroll
    for (int i2 = 0; i2 < 2; ++i2) {
        int m = m0 + ty + 16 * i2;
        if (m < M_) {
            #pragma unroll
            for (int jj = 0; jj < 4; ++jj) {
                int n = n0 + tx + 16 * jj;
                C[(size_t)m * N + n] = acc[i2][jj] + bias[n];
            }
        }
    }
}

// ---------------------------------------------------------------------------
// Attention: one block per (b,h).  S=17, DH=64.
// ---------------------------------------------------------------------------
__global__ __launch_bounds__(128)
void attn_kernel(const float* __restrict__ qkv, float* __restrict__ obuf)
{
    __shared__ float qs[S_][65], ks[S_][65], vs[S_][65], att[S_][18];
    const int bh = blockIdx.x, b = bh / H_, h = bh % H_;
    const int bq = b * S_;
    const int tid = threadIdx.x;

    for (int idx = tid; idx < S_ * 64; idx += 128) {
        int s = idx >> 6, d = idx & 63;
        size_t off = (size_t)(bq + s) * (3 * D_) + h * 64 + d;
        qs[s][d] = qkv[off];
        ks[s][d] = qkv[off + D_];
        vs[s][d] = qkv[off + 2 * D_];
    }
    __syncthreads();
    for (int t = tid; t < S_ * S_; t += 128) {
        int i = t / S_, j = t % S_;
        float sdot = 0.f;
        #pragma unroll
        for (int d = 0; d < 64; ++d) sdot = fmaf(qs[i][d], ks[j][d], sdot);
        att[i][j] = sdot * 0.125f;
    }
    __syncthreads();
    if (tid < S_) {
        float mx = -1e30f;
        for (int j = 0; j < S_; ++j) mx = fmaxf(mx, att[tid][j]);
        float ssum = 0.f;
        for (int j = 0; j < S_; ++j) { float e = expf(att[tid][j] - mx); att[tid][j] = e; ssum += e; }
        float inv = 1.0f / ssum;
        for (int j = 0; j < S_; ++j) att[tid][j] *= inv;
    }
    __syncthreads();
    for (int t = tid; t < S_ * 64; t += 128) {
        int i = t >> 6, d = t & 63;
        float s = 0.f;
        #pragma unroll
        for (int j = 0; j < S_; ++j) s = fmaf(att[i][j], vs[j][d], s);
        obuf[(size_t)(bq + i) * D_ + h * 64 + d] = s;
    }
}

// ---------------------------------------------------------------------------
// Residual + LayerNorm: a = LN(z0 + proj); optionally emit row s==0 to d_out
// ---------------------------------------------------------------------------
__global__ __launch_bounds__(256)
void resln_kernel(const float* __restrict__ z0, const float* __restrict__ proj,
                  const float* __restrict__ ln_g, const float* __restrict__ ln_b,
                  float* __restrict__ abuf, float* __restrict__ dout, int writeOut)
{
    const int r = blockIdx.x;
    __shared__ float sm[8];
    float v[3];
    #pragma unroll
    for (int p = 0; p < 3; ++p) {
        int d = threadIdx.x + 256 * p;
        v[p] = z0[(size_t)r * D_ + d] + proj[(size_t)r * D_ + d];
    }
    float sum = 0.f, ss = 0.f;
    #pragma unroll
    for (int p = 0; p < 3; ++p) { sum += v[p]; ss += v[p] * v[p]; }
    #pragma unroll
    for (int o = 32; o; o >>= 1) { sum += __shfl_down(sum, o); ss += __shfl_down(ss, o); }
    int wid = threadIdx.x >> 6, lane = threadIdx.x & 63;
    if (lane == 0) { sm[wid * 2] = sum; sm[wid * 2 + 1] = ss; }
    __syncthreads();
    sum = sm[0] + sm[2] + sm[4] + sm[6];
    ss  = sm[1] + sm[3] + sm[5] + sm[7];
    float m = sum * (1.0f / D_), rstd = rsqrtf(ss * (1.0f / D_) - m * m + 1e-5f);
    #pragma unroll
    for (int p = 0; p < 3; ++p) {
        int d = threadIdx.x + 256 * p;
        float a = (v[p] - m) * rstd * ln_g[d] + ln_b[d];
        abuf[(size_t)r * D_ + d] = a;
        if (writeOut && (r % S_) == 0) dout[(size_t)(r / S_) * D_ + d] = a;
    }
}

// ---------------------------------------------------------------------------
extern "C" void kernel_launch(void* const* d_in, const int* in_sizes, int n_in,
                              void* d_out, int out_size, void* d_ws, size_t ws_size,
                              hipStream_t stream)
{
    const float* x     = (const float*)d_in[0];
    const float* cls   = (const float*)d_in[1];
    const float* ln_g  = (const float*)d_in[2];
    const float* ln_b  = (const float*)d_in[3];
    const float* gln_g = (const float*)d_in[4];
    const float* gln_b = (const float*)d_in[5];
    const float* gW1   = (const float*)d_in[6];
    const float* gb1   = (const float*)d_in[7];
    const float* gW2   = (const float*)d_in[8];
    const float* gb2   = (const float*)d_in[9];
    const float* Wqkv  = (const float*)d_in[10];
    const float* bqkv  = (const float*)d_in[11];
    const float* Wo    = (const float*)d_in[12];
    const float* bo    = (const float*)d_in[13];
    float* out = (float*)d_out;

    float* ws   = (float*)d_ws;
    float* A1   = ws;                         // 64
    float* A2   = ws + 64;                    // 64
    float* wbuf = ws + 128;                   // 65536
    float* topv = ws + 128 + BN_;             // 256
    int*   topi = (int*)(ws + 128 + BN_ + 256);   // 256
    float* z0   = ws + 128 + BN_ + 512;       // 208896
    float* abuf = z0 + (size_t)M_ * D_;       // 208896
    float* qkvb = abuf + (size_t)M_ * D_;     // 626688
    float* obuf = qkvb + (size_t)M_ * 3 * D_; // 208896
    float* projb = obuf + (size_t)M_ * D_;    // 208896

    precompute_kernel<<<1, 64, 0, stream>>>(gW1, gln_g, gln_b, A1, A2);
    gate_kernel<<<BN_ / 64, 256, 0, stream>>>(x, gln_g, gW1, gb1, gW2, gb2, A1, A2, wbuf);
    topk_kernel<<<B_, 256, 0, stream>>>(wbuf, topv, topi);
    build_kernel<<<M_, 256, 0, stream>>>(x, cls, ln_g, ln_b, topv, topi, z0, abuf);
    for (int l = 0; l < L_; ++l) {
        gemm_kernel<<<dim3(9, 36), 256, 0, stream>>>(abuf, Wqkv + (size_t)l * 3 * D_ * D_,
                                                     bqkv + (size_t)l * 3 * D_, qkvb, 3 * D_);
        attn_kernel<<<B_ * H_, 128, 0, stream>>>(qkvb, obuf);
        gemm_kernel<<<dim3(9, 12), 256, 0, stream>>>(obuf, Wo + (size_t)l * D_ * D_,
                                                     bo + (size_t)l * D_, projb, D_);
        resln_kernel<<<M_, 256, 0, stream>>>(z0, projb, ln_g, ln_b, abuf, out,
                                             (l == L_ - 1) ? 1 : 0);
    }
}

// Round 2
// 269.206 us; speedup vs baseline: 1.4005x; 1.4005x over previous
//
#include <hip/hip_runtime.h>
#include <hip/hip_bf16.h>
#include <math.h>

#define B_   16
#define N_   4096
#define D_   768
#define H_   12
#define L_   2
#define K_   16
#define S_   17
#define M_   272          // B_*S_
#define BN_  65536        // B_*N_

typedef __bf16 bf16x8 __attribute__((ext_vector_type(8)));
typedef float  f32x4  __attribute__((ext_vector_type(4)));

static __device__ __forceinline__ unsigned short f2bf(float f) {
    __bf16 h = (__bf16)f;
    return __builtin_bit_cast(unsigned short, h);
}
static __device__ __forceinline__ float bf2f(unsigned short u) {
    __bf16 h = __builtin_bit_cast(__bf16, u);
    return (float)h;
}
static __device__ __forceinline__ unsigned long long umax64(unsigned long long a, unsigned long long b) {
    return a > b ? a : b;
}

// ---------------------------------------------------------------------------
// Gate kernel: per block 128 instances, full e=64.
//  S1 = X * W~^T  via bf16-split MFMA (xh*wh + xh*wl + xl*wh), fp32 acc.
//  Row stats + A1/A2 accumulated during staging. Epilogue: LN-fold -> GELU ->
//  dot gW2 -> sigmoid -> wbuf.
// ---------------------------------------------------------------------------
__global__ __launch_bounds__(256)
void gate_kernel(const float* __restrict__ x,
                 const float* __restrict__ gln_g,
                 const float* __restrict__ gln_b,
                 const float* __restrict__ gW1,
                 const float* __restrict__ gb1,
                 const float* __restrict__ gW2,
                 const float* __restrict__ gb2,
                 float* __restrict__ wbuf)
{
    __shared__ unsigned short smem[24576];   // 49152 B
    unsigned short* Xh = smem;               // [128][64] bf16, swizzled
    unsigned short* Xl = smem + 8192;
    unsigned short* Wh = smem + 16384;       // [64][64]
    unsigned short* Wl = smem + 20480;
    char* XhB = (char*)Xh; char* XlB = (char*)Xl;
    char* WhB = (char*)Wh; char* WlB = (char*)Wl;

    const int t   = threadIdx.x;
    const int bn0 = blockIdx.x * 128;

    // staging roles
    const int trow  = t >> 1;            // 0..127
    const int thalf = (t & 1) * 32;      // k-half within 64
    const int te    = t >> 2;            // 0..63  (W row / e)
    const int tq    = (t & 3) * 16;      // k-quarter within 64

    const float* xrow = x + (size_t)(bn0 + trow) * D_ + thalf;
    const float* wrow = gW1 + (size_t)te * D_ + tq;

    // MFMA roles
    const int wv = t >> 6;               // wave 0..3
    const int l  = t & 63;
    const int fr = l & 15;
    const int fq = l >> 4;

    f32x4 acc[2][4];
    #pragma unroll
    for (int mi = 0; mi < 2; ++mi)
        #pragma unroll
        for (int ni = 0; ni < 4; ++ni) {
            f32x4 z = {0.f, 0.f, 0.f, 0.f};
            acc[mi][ni] = z;
        }

    float sxp = 0.f, sxxp = 0.f;         // half-row stats
    float a1p = 0.f, a2p = 0.f;          // per-(e, quarter) partials

    for (int kt = 0; kt < 12; ++kt) {
        __syncthreads();
        // ---- stage X (128 x 64 floats -> bf16 hi/lo) ----
        const float* src = xrow + kt * 64;
        #pragma unroll
        for (int j = 0; j < 8; ++j) {
            float4 v = *(const float4*)(src + j * 4);
            sxp  += v.x + v.y + v.z + v.w;
            sxxp += v.x * v.x + v.y * v.y + v.z * v.z + v.w * v.w;
            ushort4 hh, ll;
            hh.x = f2bf(v.x); ll.x = f2bf(v.x - bf2f(hh.x));
            hh.y = f2bf(v.y); ll.y = f2bf(v.y - bf2f(hh.y));
            hh.z = f2bf(v.z); ll.z = f2bf(v.z - bf2f(hh.z));
            hh.w = f2bf(v.w); ll.w = f2bf(v.w - bf2f(hh.w));
            int byte = trow * 128 + (thalf + j * 4) * 2;
            int sw   = byte ^ ((trow & 7) << 4);
            *(ushort4*)(XhB + sw) = hh;
            *(ushort4*)(XlB + sw) = ll;
        }
        // ---- stage W~ = gln_g * gW1 (64 x 64) ----
        const float* wsrc = wrow + kt * 64;
        const float* gsrc = gln_g + kt * 64 + tq;
        const float* bsrc = gln_b + kt * 64 + tq;
        #pragma unroll
        for (int j = 0; j < 4; ++j) {
            float4 w4 = *(const float4*)(wsrc + j * 4);
            float4 g4 = *(const float4*)(gsrc + j * 4);
            float4 b4 = *(const float4*)(bsrc + j * 4);
            float4 wt;
            wt.x = w4.x * g4.x; wt.y = w4.y * g4.y;
            wt.z = w4.z * g4.z; wt.w = w4.w * g4.w;
            a1p += wt.x + wt.y + wt.z + wt.w;
            a2p += b4.x * w4.x + b4.y * w4.y + b4.z * w4.z + b4.w * w4.w;
            ushort4 hh, ll;
            hh.x = f2bf(wt.x); ll.x = f2bf(wt.x - bf2f(hh.x));
            hh.y = f2bf(wt.y); ll.y = f2bf(wt.y - bf2f(hh.y));
            hh.z = f2bf(wt.z); ll.z = f2bf(wt.z - bf2f(hh.z));
            hh.w = f2bf(wt.w); ll.w = f2bf(wt.w - bf2f(hh.w));
            int byte = te * 128 + (tq + j * 4) * 2;
            int sw   = byte ^ ((te & 7) << 4);
            *(ushort4*)(WhB + sw) = hh;
            *(ushort4*)(WlB + sw) = ll;
        }
        __syncthreads();
        // ---- MFMA phase: two k-steps of 32 ----
        #pragma unroll
        for (int ks = 0; ks < 2; ++ks) {
            int k0 = ks * 32 + fq * 8;
            bf16x8 ah[2], al[2], bh[4], bl[4];
            #pragma unroll
            for (int mi = 0; mi < 2; ++mi) {
                int r    = wv * 32 + mi * 16 + fr;
                int byte = (r * 128 + k0 * 2) ^ ((r & 7) << 4);
                ah[mi] = *(const bf16x8*)(XhB + byte);
                al[mi] = *(const bf16x8*)(XlB + byte);
            }
            #pragma unroll
            for (int ni = 0; ni < 4; ++ni) {
                int e    = ni * 16 + fr;
                int byte = (e * 128 + k0 * 2) ^ ((e & 7) << 4);
                bh[ni] = *(const bf16x8*)(WhB + byte);
                bl[ni] = *(const bf16x8*)(WlB + byte);
            }
            #pragma unroll
            for (int mi = 0; mi < 2; ++mi)
                #pragma unroll
                for (int ni = 0; ni < 4; ++ni) {
                    acc[mi][ni] = __builtin_amdgcn_mfma_f32_16x16x32_bf16(ah[mi], bh[ni], acc[mi][ni], 0, 0, 0);
                    acc[mi][ni] = __builtin_amdgcn_mfma_f32_16x16x32_bf16(ah[mi], bl[ni], acc[mi][ni], 0, 0, 0);
                    acc[mi][ni] = __builtin_amdgcn_mfma_f32_16x16x32_bf16(al[mi], bh[ni], acc[mi][ni], 0, 0, 0);
                }
        }
    }
    __syncthreads();

    // ---- reductions in reused LDS ----
    float* F    = (float*)smem;
    float* mS   = F;          // 128
    float* rS   = F + 128;    // 128
    float* A1s  = F + 256;    // 64
    float* A2s  = F + 320;    // 64
    float* redS = F + 384;    // [128][2]
    float* redQ = F + 640;    // [128][2]
    float* rA1  = F + 896;    // [64][4]
    float* rA2  = F + 1152;   // [64][4]

    redS[trow * 2 + (t & 1)] = sxp;
    redQ[trow * 2 + (t & 1)] = sxxp;
    rA1[te * 4 + (t & 3)] = a1p;
    rA2[te * 4 + (t & 3)] = a2p;
    __syncthreads();
    if (t < 128) {
        float s = redS[t * 2] + redS[t * 2 + 1];
        float q = redQ[t * 2] + redQ[t * 2 + 1];
        float m = s * (1.0f / D_);
        mS[t] = m;
        rS[t] = rsqrtf(q * (1.0f / D_) - m * m + 1e-5f);
    }
    if (t < 64) {
        A1s[t] = rA1[t * 4] + rA1[t * 4 + 1] + rA1[t * 4 + 2] + rA1[t * 4 + 3];
        A2s[t] = rA2[t * 4] + rA2[t * 4 + 1] + rA2[t * 4 + 2] + rA2[t * 4 + 3];
    }
    __syncthreads();

    // ---- epilogue ----
    float w2v[4], a1v[4], a2b[4];
    #pragma unroll
    for (int ni = 0; ni < 4; ++ni) {
        int e = ni * 16 + fr;
        w2v[ni] = gW2[e];
        a1v[ni] = A1s[e];
        a2b[ni] = A2s[e] + gb1[e];
    }
    float gb2v = gb2[0];

    #pragma unroll
    for (int mi = 0; mi < 2; ++mi) {
        #pragma unroll
        for (int j = 0; j < 4; ++j) {
            int inst = wv * 32 + mi * 16 + fq * 4 + j;
            float m  = mS[inst], rs = rS[inst];
            float tp = 0.f;
            #pragma unroll
            for (int ni = 0; ni < 4; ++ni) {
                float h  = rs * (acc[mi][ni][j] - m * a1v[ni]) + a2b[ni];
                float hg = 0.5f * h * (1.0f + erff(h * 0.70710678118654752f));
                tp = fmaf(hg, w2v[ni], tp);
            }
            tp += __shfl_xor(tp, 1);
            tp += __shfl_xor(tp, 2);
            tp += __shfl_xor(tp, 4);
            tp += __shfl_xor(tp, 8);
            if (fr == 0) wbuf[bn0 + inst] = 1.0f / (1.0f + expf(-(tp + gb2v)));
        }
    }
}

// ---------------------------------------------------------------------------
// Top-16 per bag: 1024 threads, 4 elems/thread in registers, u64 packed keys.
// key = (float_bits(w) << 12) | (4095 - idx)  -> max = largest w, tie lower i.
// ---------------------------------------------------------------------------
__global__ __launch_bounds__(1024)
void topk_kernel(const float* __restrict__ wbuf,
                 float* __restrict__ topv, int* __restrict__ topi)
{
    const int b = blockIdx.x, t = threadIdx.x;
    const int lane = t & 63, wid = t >> 6;
    __shared__ unsigned long long wred[16];
    __shared__ unsigned long long winkey;

    unsigned long long key[4];
    float4 v = *(const float4*)&wbuf[(size_t)b * N_ + t * 4];
    key[0] = ((unsigned long long)__float_as_uint(v.x) << 12) | (unsigned long long)(4095 - (t * 4 + 0));
    key[1] = ((unsigned long long)__float_as_uint(v.y) << 12) | (unsigned long long)(4095 - (t * 4 + 1));
    key[2] = ((unsigned long long)__float_as_uint(v.z) << 12) | (unsigned long long)(4095 - (t * 4 + 2));
    key[3] = ((unsigned long long)__float_as_uint(v.w) << 12) | (unsigned long long)(4095 - (t * 4 + 3));

    for (int k = 0; k < K_; ++k) {
        unsigned long long kk = umax64(umax64(key[0], key[1]), umax64(key[2], key[3]));
        #pragma unroll
        for (int o = 1; o < 64; o <<= 1) kk = umax64(kk, (unsigned long long)__shfl_xor(kk, o));
        if (lane == 0) wred[wid] = kk;
        __syncthreads();
        if (t == 0) {
            unsigned long long m = wred[0];
            #pragma unroll
            for (int i = 1; i < 16; ++i) m = umax64(m, wred[i]);
            winkey = m;
            int wi = 4095 - (int)(m & 0xfffULL);
            topv[b * K_ + k] = __uint_as_float((unsigned int)(m >> 12));
            topi[b * K_ + k] = wi;
        }
        __syncthreads();
        unsigned long long m = winkey;
        int wi = 4095 - (int)(m & 0xfffULL);
        if ((wi >> 2) == t) key[wi & 3] = 0ULL;
    }
}

// ---------------------------------------------------------------------------
// Build seq = [cls, x[topi]*topv], LayerNorm -> z0, a = z0
// ---------------------------------------------------------------------------
__global__ __launch_bounds__(256)
void build_kernel(const float* __restrict__ x, const float* __restrict__ cls,
                  const float* __restrict__ ln_g, const float* __restrict__ ln_b,
                  const float* __restrict__ topv, const int* __restrict__ topi,
                  float* __restrict__ z0, float* __restrict__ abuf)
{
    const int r = blockIdx.x, b = r / S_, s = r % S_;
    __shared__ float sm[8];
    float v[3];
    if (s == 0) {
        #pragma unroll
        for (int p = 0; p < 3; ++p) v[p] = cls[threadIdx.x + 256 * p];
    } else {
        int   idx = topi[b * K_ + s - 1];
        float tv  = topv[b * K_ + s - 1];
        const float* row = &x[((size_t)b * N_ + idx) * D_];
        #pragma unroll
        for (int p = 0; p < 3; ++p) v[p] = row[threadIdx.x + 256 * p] * tv;
    }
    float sum = 0.f, ss = 0.f;
    #pragma unroll
    for (int p = 0; p < 3; ++p) { sum += v[p]; ss += v[p] * v[p]; }
    #pragma unroll
    for (int o = 32; o; o >>= 1) { sum += __shfl_down(sum, o); ss += __shfl_down(ss, o); }
    int wid = threadIdx.x >> 6, lane = threadIdx.x & 63;
    if (lane == 0) { sm[wid * 2] = sum; sm[wid * 2 + 1] = ss; }
    __syncthreads();
    sum = sm[0] + sm[2] + sm[4] + sm[6];
    ss  = sm[1] + sm[3] + sm[5] + sm[7];
    float m = sum * (1.0f / D_), rstd = rsqrtf(ss * (1.0f / D_) - m * m + 1e-5f);
    #pragma unroll
    for (int p = 0; p < 3; ++p) {
        int d = threadIdx.x + 256 * p;
        float z = (v[p] - m) * rstd * ln_g[d] + ln_b[d];
        z0[(size_t)r * D_ + d]   = z;
        abuf[(size_t)r * D_ + d] = z;
    }
}

// ---------------------------------------------------------------------------
// GEMM: C[m][n] = sum_k A[m][k]*W[n][k] + bias[n] ; M=272, K=768, N param
// ---------------------------------------------------------------------------
__global__ __launch_bounds__(256)
void gemm_kernel(const float* __restrict__ A, const float* __restrict__ W,
                 const float* __restrict__ bias, float* __restrict__ C, int N)
{
    __shared__ float As[32 * 68];
    __shared__ float Ws2[64 * 68];
    const int tid = threadIdx.x;
    const int ty = tid >> 4, tx = tid & 15;
    const int m0 = blockIdx.x * 32, n0 = blockIdx.y * 64;
    const int cc = tx * 4;
    float acc[2][4] = {};

    for (int kt = 0; kt < 12; ++kt) {
        __syncthreads();
        #pragma unroll
        for (int p = 0; p < 2; ++p) {
            int r = ty + p * 16, m = m0 + r;
            float4 av = (m < M_) ? *(const float4*)&A[(size_t)m * D_ + kt * 64 + cc]
                                 : make_float4(0.f, 0.f, 0.f, 0.f);
            As[r * 68 + cc + 0] = av.x; As[r * 68 + cc + 1] = av.y;
            As[r * 68 + cc + 2] = av.z; As[r * 68 + cc + 3] = av.w;
        }
        #pragma unroll
        for (int p = 0; p < 4; ++p) {
            int r = ty + p * 16;
            float4 wv = *(const float4*)&W[(size_t)(n0 + r) * D_ + kt * 64 + cc];
            Ws2[r * 68 + cc + 0] = wv.x; Ws2[r * 68 + cc + 1] = wv.y;
            Ws2[r * 68 + cc + 2] = wv.z; Ws2[r * 68 + cc + 3] = wv.w;
        }
        __syncthreads();
        #pragma unroll
        for (int d4 = 0; d4 < 16; ++d4) {
            int d = d4 * 4;
            float4 a0 = *(float4*)&As[ty * 68 + d];
            float4 a1 = *(float4*)&As[(ty + 16) * 68 + d];
            #pragma unroll
            for (int jj = 0; jj < 4; ++jj) {
                float4 wf = *(float4*)&Ws2[(tx + 16 * jj) * 68 + d];
                acc[0][jj] = fmaf(a0.x, wf.x, acc[0][jj]);
                acc[0][jj] = fmaf(a0.y, wf.y, acc[0][jj]);
                acc[0][jj] = fmaf(a0.z, wf.z, acc[0][jj]);
                acc[0][jj] = fmaf(a0.w, wf.w, acc[0][jj]);
                acc[1][jj] = fmaf(a1.x, wf.x, acc[1][jj]);
                acc[1][jj] = fmaf(a1.y, wf.y, acc[1][jj]);
                acc[1][jj] = fmaf(a1.z, wf.z, acc[1][jj]);
                acc[1][jj] = fmaf(a1.w, wf.w, acc[1][jj]);
            }
        }
    }
    #pragma unroll
    for (int i2 = 0; i2 < 2; ++i2) {
        int m = m0 + ty + 16 * i2;
        if (m < M_) {
            #pragma unroll
            for (int jj = 0; jj < 4; ++jj) {
                int n = n0 + tx + 16 * jj;
                C[(size_t)m * N + n] = acc[i2][jj] + bias[n];
            }
        }
    }
}

// ---------------------------------------------------------------------------
// Attention: one block per (b,h).  S=17, DH=64.
// ---------------------------------------------------------------------------
__global__ __launch_bounds__(128)
void attn_kernel(const float* __restrict__ qkv, float* __restrict__ obuf)
{
    __shared__ float qs[S_][65], ks[S_][65], vs[S_][65], att[S_][18];
    const int bh = blockIdx.x, b = bh / H_, h = bh % H_;
    const int bq = b * S_;
    const int tid = threadIdx.x;

    for (int idx = tid; idx < S_ * 64; idx += 128) {
        int s = idx >> 6, d = idx & 63;
        size_t off = (size_t)(bq + s) * (3 * D_) + h * 64 + d;
        qs[s][d] = qkv[off];
        ks[s][d] = qkv[off + D_];
        vs[s][d] = qkv[off + 2 * D_];
    }
    __syncthreads();
    for (int t = tid; t < S_ * S_; t += 128) {
        int i = t / S_, j = t % S_;
        float sdot = 0.f;
        #pragma unroll
        for (int d = 0; d < 64; ++d) sdot = fmaf(qs[i][d], ks[j][d], sdot);
        att[i][j] = sdot * 0.125f;
    }
    __syncthreads();
    if (tid < S_) {
        float mx = -1e30f;
        for (int j = 0; j < S_; ++j) mx = fmaxf(mx, att[tid][j]);
        float ssum = 0.f;
        for (int j = 0; j < S_; ++j) { float e = expf(att[tid][j] - mx); att[tid][j] = e; ssum += e; }
        float inv = 1.0f / ssum;
        for (int j = 0; j < S_; ++j) att[tid][j] *= inv;
    }
    __syncthreads();
    for (int t = tid; t < S_ * 64; t += 128) {
        int i = t >> 6, d = t & 63;
        float s = 0.f;
        #pragma unroll
        for (int j = 0; j < S_; ++j) s = fmaf(att[i][j], vs[j][d], s);
        obuf[(size_t)(bq + i) * D_ + h * 64 + d] = s;
    }
}

// ---------------------------------------------------------------------------
// Residual + LayerNorm: a = LN(z0 + proj); optionally emit row s==0 to d_out
// ---------------------------------------------------------------------------
__global__ __launch_bounds__(256)
void resln_kernel(const float* __restrict__ z0, const float* __restrict__ proj,
                  const float* __restrict__ ln_g, const float* __restrict__ ln_b,
                  float* __restrict__ abuf, float* __restrict__ dout, int writeOut)
{
    const int r = blockIdx.x;
    __shared__ float sm[8];
    float v[3];
    #pragma unroll
    for (int p = 0; p < 3; ++p) {
        int d = threadIdx.x + 256 * p;
        v[p] = z0[(size_t)r * D_ + d] + proj[(size_t)r * D_ + d];
    }
    float sum = 0.f, ss = 0.f;
    #pragma unroll
    for (int p = 0; p < 3; ++p) { sum += v[p]; ss += v[p] * v[p]; }
    #pragma unroll
    for (int o = 32; o; o >>= 1) { sum += __shfl_down(sum, o); ss += __shfl_down(ss, o); }
    int wid = threadIdx.x >> 6, lane = threadIdx.x & 63;
    if (lane == 0) { sm[wid * 2] = sum; sm[wid * 2 + 1] = ss; }
    __syncthreads();
    sum = sm[0] + sm[2] + sm[4] + sm[6];
    ss  = sm[1] + sm[3] + sm[5] + sm[7];
    float m = sum * (1.0f / D_), rstd = rsqrtf(ss * (1.0f / D_) - m * m + 1e-5f);
    #pragma unroll
    for (int p = 0; p < 3; ++p) {
        int d = threadIdx.x + 256 * p;
        float a = (v[p] - m) * rstd * ln_g[d] + ln_b[d];
        abuf[(size_t)r * D_ + d] = a;
        if (writeOut && (r % S_) == 0) dout[(size_t)(r / S_) * D_ + d] = a;
    }
}

// ---------------------------------------------------------------------------
extern "C" void kernel_launch(void* const* d_in, const int* in_sizes, int n_in,
                              void* d_out, int out_size, void* d_ws, size_t ws_size,
                              hipStream_t stream)
{
    const float* x     = (const float*)d_in[0];
    const float* cls   = (const float*)d_in[1];
    const float* ln_g  = (const float*)d_in[2];
    const float* ln_b  = (const float*)d_in[3];
    const float* gln_g = (const float*)d_in[4];
    const float* gln_b = (const float*)d_in[5];
    const float* gW1   = (const float*)d_in[6];
    const float* gb1   = (const float*)d_in[7];
    const float* gW2   = (const float*)d_in[8];
    const float* gb2   = (const float*)d_in[9];
    const float* Wqkv  = (const float*)d_in[10];
    const float* bqkv  = (const float*)d_in[11];
    const float* Wo    = (const float*)d_in[12];
    const float* bo    = (const float*)d_in[13];
    float* out = (float*)d_out;

    float* ws   = (float*)d_ws;
    float* wbuf = ws;                         // 65536
    float* topv = ws + BN_;                   // 256
    int*   topi = (int*)(ws + BN_ + 256);     // 256
    float* z0   = ws + BN_ + 512;             // 208896
    float* abuf = z0 + (size_t)M_ * D_;
    float* qkvb = abuf + (size_t)M_ * D_;     // M*2304
    float* obuf = qkvb + (size_t)M_ * 3 * D_;
    float* projb = obuf + (size_t)M_ * D_;

    gate_kernel<<<BN_ / 128, 256, 0, stream>>>(x, gln_g, gln_b, gW1, gb1, gW2, gb2, wbuf);
    topk_kernel<<<B_, 1024, 0, stream>>>(wbuf, topv, topi);
    build_kernel<<<M_, 256, 0, stream>>>(x, cls, ln_g, ln_b, topv, topi, z0, abuf);
    for (int l = 0; l < L_; ++l) {
        gemm_kernel<<<dim3(9, 36), 256, 0, stream>>>(abuf, Wqkv + (size_t)l * 3 * D_ * D_,
                                                     bqkv + (size_t)l * 3 * D_, qkvb, 3 * D_);
        attn_kernel<<<B_ * H_, 128, 0, stream>>>(qkvb, obuf);
        gemm_kernel<<<dim3(9, 12), 256, 0, stream>>>(obuf, Wo + (size_t)l * D_ * D_,
                                                     bo + (size_t)l * D_, projb, D_);
        resln_kernel<<<M_, 256, 0, stream>>>(z0, projb, ln_g, ln_b, abuf, out,
                                             (l == L_ - 1) ? 1 : 0);
    }
}

// Round 3
// 186.987 us; speedup vs baseline: 2.0163x; 1.4397x over previous
//
#include <hip/hip_runtime.h>
#include <hip/hip_bf16.h>
#include <math.h>

#define B_   16
#define N_   4096
#define D_   768
#define H_   12
#define L_   2
#define K_   16
#define S_   17
#define M_   272          // B_*S_
#define BN_  65536        // B_*N_

typedef __bf16 bf16x8 __attribute__((ext_vector_type(8)));
typedef float  f32x4  __attribute__((ext_vector_type(4)));

static __device__ __forceinline__ unsigned short f2bf(float f) {
    __bf16 h = (__bf16)f;
    return __builtin_bit_cast(unsigned short, h);
}
static __device__ __forceinline__ float bf2f(unsigned short u) {
    __bf16 h = __builtin_bit_cast(__bf16, u);
    return (float)h;
}
static __device__ __forceinline__ unsigned long long umax64(unsigned long long a, unsigned long long b) {
    return a > b ? a : b;
}

// ---------------------------------------------------------------------------
// Gate kernel (unchanged from round 2): bf16-split MFMA, LN-fold, GELU, sigmoid
// ---------------------------------------------------------------------------
__global__ __launch_bounds__(256)
void gate_kernel(const float* __restrict__ x,
                 const float* __restrict__ gln_g,
                 const float* __restrict__ gln_b,
                 const float* __restrict__ gW1,
                 const float* __restrict__ gb1,
                 const float* __restrict__ gW2,
                 const float* __restrict__ gb2,
                 float* __restrict__ wbuf)
{
    __shared__ unsigned short smem[24576];   // 49152 B
    unsigned short* Xh = smem;               // [128][64] bf16, swizzled
    unsigned short* Xl = smem + 8192;
    unsigned short* Wh = smem + 16384;       // [64][64]
    unsigned short* Wl = smem + 20480;
    char* XhB = (char*)Xh; char* XlB = (char*)Xl;
    char* WhB = (char*)Wh; char* WlB = (char*)Wl;

    const int t   = threadIdx.x;
    const int bn0 = blockIdx.x * 128;

    const int trow  = t >> 1;            // 0..127
    const int thalf = (t & 1) * 32;      // k-half within 64
    const int te    = t >> 2;            // 0..63  (W row / e)
    const int tq    = (t & 3) * 16;      // k-quarter within 64

    const float* xrow = x + (size_t)(bn0 + trow) * D_ + thalf;
    const float* wrow = gW1 + (size_t)te * D_ + tq;

    const int wv = t >> 6;               // wave 0..3
    const int l  = t & 63;
    const int fr = l & 15;
    const int fq = l >> 4;

    f32x4 acc[2][4];
    #pragma unroll
    for (int mi = 0; mi < 2; ++mi)
        #pragma unroll
        for (int ni = 0; ni < 4; ++ni) {
            f32x4 z = {0.f, 0.f, 0.f, 0.f};
            acc[mi][ni] = z;
        }

    float sxp = 0.f, sxxp = 0.f;
    float a1p = 0.f, a2p = 0.f;

    for (int kt = 0; kt < 12; ++kt) {
        __syncthreads();
        const float* src = xrow + kt * 64;
        #pragma unroll
        for (int j = 0; j < 8; ++j) {
            float4 v = *(const float4*)(src + j * 4);
            sxp  += v.x + v.y + v.z + v.w;
            sxxp += v.x * v.x + v.y * v.y + v.z * v.z + v.w * v.w;
            ushort4 hh, ll;
            hh.x = f2bf(v.x); ll.x = f2bf(v.x - bf2f(hh.x));
            hh.y = f2bf(v.y); ll.y = f2bf(v.y - bf2f(hh.y));
            hh.z = f2bf(v.z); ll.z = f2bf(v.z - bf2f(hh.z));
            hh.w = f2bf(v.w); ll.w = f2bf(v.w - bf2f(hh.w));
            int byte = trow * 128 + (thalf + j * 4) * 2;
            int sw   = byte ^ ((trow & 7) << 4);
            *(ushort4*)(XhB + sw) = hh;
            *(ushort4*)(XlB + sw) = ll;
        }
        const float* wsrc = wrow + kt * 64;
        const float* gsrc = gln_g + kt * 64 + tq;
        const float* bsrc = gln_b + kt * 64 + tq;
        #pragma unroll
        for (int j = 0; j < 4; ++j) {
            float4 w4 = *(const float4*)(wsrc + j * 4);
            float4 g4 = *(const float4*)(gsrc + j * 4);
            float4 b4 = *(const float4*)(bsrc + j * 4);
            float4 wt;
            wt.x = w4.x * g4.x; wt.y = w4.y * g4.y;
            wt.z = w4.z * g4.z; wt.w = w4.w * g4.w;
            a1p += wt.x + wt.y + wt.z + wt.w;
            a2p += b4.x * w4.x + b4.y * w4.y + b4.z * w4.z + b4.w * w4.w;
            ushort4 hh, ll;
            hh.x = f2bf(wt.x); ll.x = f2bf(wt.x - bf2f(hh.x));
            hh.y = f2bf(wt.y); ll.y = f2bf(wt.y - bf2f(hh.y));
            hh.z = f2bf(wt.z); ll.z = f2bf(wt.z - bf2f(hh.z));
            hh.w = f2bf(wt.w); ll.w = f2bf(wt.w - bf2f(hh.w));
            int byte = te * 128 + (tq + j * 4) * 2;
            int sw   = byte ^ ((te & 7) << 4);
            *(ushort4*)(WhB + sw) = hh;
            *(ushort4*)(WlB + sw) = ll;
        }
        __syncthreads();
        #pragma unroll
        for (int ks = 0; ks < 2; ++ks) {
            int k0 = ks * 32 + fq * 8;
            bf16x8 ah[2], al[2], bh[4], bl[4];
            #pragma unroll
            for (int mi = 0; mi < 2; ++mi) {
                int r    = wv * 32 + mi * 16 + fr;
                int byte = (r * 128 + k0 * 2) ^ ((r & 7) << 4);
                ah[mi] = *(const bf16x8*)(XhB + byte);
                al[mi] = *(const bf16x8*)(XlB + byte);
            }
            #pragma unroll
            for (int ni = 0; ni < 4; ++ni) {
                int e    = ni * 16 + fr;
                int byte = (e * 128 + k0 * 2) ^ ((e & 7) << 4);
                bh[ni] = *(const bf16x8*)(WhB + byte);
                bl[ni] = *(const bf16x8*)(WlB + byte);
            }
            #pragma unroll
            for (int mi = 0; mi < 2; ++mi)
                #pragma unroll
                for (int ni = 0; ni < 4; ++ni) {
                    acc[mi][ni] = __builtin_amdgcn_mfma_f32_16x16x32_bf16(ah[mi], bh[ni], acc[mi][ni], 0, 0, 0);
                    acc[mi][ni] = __builtin_amdgcn_mfma_f32_16x16x32_bf16(ah[mi], bl[ni], acc[mi][ni], 0, 0, 0);
                    acc[mi][ni] = __builtin_amdgcn_mfma_f32_16x16x32_bf16(al[mi], bh[ni], acc[mi][ni], 0, 0, 0);
                }
        }
    }
    __syncthreads();

    float* F    = (float*)smem;
    float* mS   = F;          // 128
    float* rS   = F + 128;    // 128
    float* A1s  = F + 256;    // 64
    float* A2s  = F + 320;    // 64
    float* redS = F + 384;    // [128][2]
    float* redQ = F + 640;    // [128][2]
    float* rA1  = F + 896;    // [64][4]
    float* rA2  = F + 1152;   // [64][4]

    redS[trow * 2 + (t & 1)] = sxp;
    redQ[trow * 2 + (t & 1)] = sxxp;
    rA1[te * 4 + (t & 3)] = a1p;
    rA2[te * 4 + (t & 3)] = a2p;
    __syncthreads();
    if (t < 128) {
        float s = redS[t * 2] + redS[t * 2 + 1];
        float q = redQ[t * 2] + redQ[t * 2 + 1];
        float m = s * (1.0f / D_);
        mS[t] = m;
        rS[t] = rsqrtf(q * (1.0f / D_) - m * m + 1e-5f);
    }
    if (t < 64) {
        A1s[t] = rA1[t * 4] + rA1[t * 4 + 1] + rA1[t * 4 + 2] + rA1[t * 4 + 3];
        A2s[t] = rA2[t * 4] + rA2[t * 4 + 1] + rA2[t * 4 + 2] + rA2[t * 4 + 3];
    }
    __syncthreads();

    float w2v[4], a1v[4], a2b[4];
    #pragma unroll
    for (int ni = 0; ni < 4; ++ni) {
        int e = ni * 16 + fr;
        w2v[ni] = gW2[e];
        a1v[ni] = A1s[e];
        a2b[ni] = A2s[e] + gb1[e];
    }
    float gb2v = gb2[0];

    #pragma unroll
    for (int mi = 0; mi < 2; ++mi) {
        #pragma unroll
        for (int j = 0; j < 4; ++j) {
            int inst = wv * 32 + mi * 16 + fq * 4 + j;
            float m = mS[inst], rs = rS[inst];
            float tp = 0.f;
            #pragma unroll
            for (int ni = 0; ni < 4; ++ni) {
                float h  = rs * (acc[mi][ni][j] - m * a1v[ni]) + a2b[ni];
                float hg = 0.5f * h * (1.0f + erff(h * 0.70710678118654752f));
                tp = fmaf(hg, w2v[ni], tp);
            }
            tp += __shfl_xor(tp, 1);
            tp += __shfl_xor(tp, 2);
            tp += __shfl_xor(tp, 4);
            tp += __shfl_xor(tp, 8);
            if (fr == 0) wbuf[bn0 + inst] = 1.0f / (1.0f + expf(-(tp + gb2v)));
        }
    }
}

// ---------------------------------------------------------------------------
// Top-16 per bag (unchanged from round 2)
// ---------------------------------------------------------------------------
__global__ __launch_bounds__(1024)
void topk_kernel(const float* __restrict__ wbuf,
                 float* __restrict__ topv, int* __restrict__ topi)
{
    const int b = blockIdx.x, t = threadIdx.x;
    const int lane = t & 63, wid = t >> 6;
    __shared__ unsigned long long wred[16];
    __shared__ unsigned long long winkey;

    unsigned long long key[4];
    float4 v = *(const float4*)&wbuf[(size_t)b * N_ + t * 4];
    key[0] = ((unsigned long long)__float_as_uint(v.x) << 12) | (unsigned long long)(4095 - (t * 4 + 0));
    key[1] = ((unsigned long long)__float_as_uint(v.y) << 12) | (unsigned long long)(4095 - (t * 4 + 1));
    key[2] = ((unsigned long long)__float_as_uint(v.z) << 12) | (unsigned long long)(4095 - (t * 4 + 2));
    key[3] = ((unsigned long long)__float_as_uint(v.w) << 12) | (unsigned long long)(4095 - (t * 4 + 3));

    for (int k = 0; k < K_; ++k) {
        unsigned long long kk = umax64(umax64(key[0], key[1]), umax64(key[2], key[3]));
        #pragma unroll
        for (int o = 1; o < 64; o <<= 1) kk = umax64(kk, (unsigned long long)__shfl_xor(kk, o));
        if (lane == 0) wred[wid] = kk;
        __syncthreads();
        if (t == 0) {
            unsigned long long m = wred[0];
            #pragma unroll
            for (int i = 1; i < 16; ++i) m = umax64(m, wred[i]);
            winkey = m;
            int wi = 4095 - (int)(m & 0xfffULL);
            topv[b * K_ + k] = __uint_as_float((unsigned int)(m >> 12));
            topi[b * K_ + k] = wi;
        }
        __syncthreads();
        unsigned long long m = winkey;
        int wi = 4095 - (int)(m & 0xfffULL);
        if ((wi >> 2) == t) key[wi & 3] = 0ULL;
    }
}

// ---------------------------------------------------------------------------
// Build seq = [cls, x[topi]*topv], LayerNorm -> z0, a = z0 (unchanged)
// ---------------------------------------------------------------------------
__global__ __launch_bounds__(256)
void build_kernel(const float* __restrict__ x, const float* __restrict__ cls,
                  const float* __restrict__ ln_g, const float* __restrict__ ln_b,
                  const float* __restrict__ topv, const int* __restrict__ topi,
                  float* __restrict__ z0, float* __restrict__ abuf)
{
    const int r = blockIdx.x, b = r / S_, s = r % S_;
    __shared__ float sm[8];
    float v[3];
    if (s == 0) {
        #pragma unroll
        for (int p = 0; p < 3; ++p) v[p] = cls[threadIdx.x + 256 * p];
    } else {
        int   idx = topi[b * K_ + s - 1];
        float tv  = topv[b * K_ + s - 1];
        const float* row = &x[((size_t)b * N_ + idx) * D_];
        #pragma unroll
        for (int p = 0; p < 3; ++p) v[p] = row[threadIdx.x + 256 * p] * tv;
    }
    float sum = 0.f, ss = 0.f;
    #pragma unroll
    for (int p = 0; p < 3; ++p) { sum += v[p]; ss += v[p] * v[p]; }
    #pragma unroll
    for (int o = 32; o; o >>= 1) { sum += __shfl_down(sum, o); ss += __shfl_down(ss, o); }
    int wid = threadIdx.x >> 6, lane = threadIdx.x & 63;
    if (lane == 0) { sm[wid * 2] = sum; sm[wid * 2 + 1] = ss; }
    __syncthreads();
    sum = sm[0] + sm[2] + sm[4] + sm[6];
    ss  = sm[1] + sm[3] + sm[5] + sm[7];
    float m = sum * (1.0f / D_), rstd = rsqrtf(ss * (1.0f / D_) - m * m + 1e-5f);
    #pragma unroll
    for (int p = 0; p < 3; ++p) {
        int d = threadIdx.x + 256 * p;
        float z = (v[p] - m) * rstd * ln_g[d] + ln_b[d];
        z0[(size_t)r * D_ + d]   = z;
        abuf[(size_t)r * D_ + d] = z;
    }
}

// ---------------------------------------------------------------------------
// MFMA GEMM (bf16-split, 3-pass): C[m][n] = sum_k A[m][k]*W[n][k] + bias[n]
// A: [272][768] fp32, W: [N][768] fp32.  Tile 64x64, BK=64, 256 thr, 4 waves.
// In-kernel fp32->bf16 hi/lo conversion; XOR-swizzled LDS; next-tile register
// prefetch so global latency hides under MFMA (these run ~1 block/CU).
// ---------------------------------------------------------------------------
__global__ __launch_bounds__(256)
void gemm_mfma(const float* __restrict__ A, const float* __restrict__ W,
               const float* __restrict__ bias, float* __restrict__ C, int N)
{
    __shared__ unsigned short smem[16384];   // 32 KB: Ah|Al|Wh|Wl each [64][64]
    char* AhB = (char*)smem;
    char* AlB = (char*)(smem + 4096);
    char* WhB = (char*)(smem + 8192);
    char* WlB = (char*)(smem + 12288);

    const int t  = threadIdx.x;
    const int m0 = blockIdx.x * 64, n0 = blockIdx.y * 64;

    // staging role: row sr (0..63), 16-elem col group sc
    const int sr = t >> 2;
    const int sc = (t & 3) * 16;
    const int gm = m0 + sr;
    const bool aok = (gm < M_);
    const float* asrc = A + (size_t)gm * D_ + sc;
    const float* wsrc = W + (size_t)(n0 + sr) * D_ + sc;

    // MFMA role
    const int wv = t >> 6, l = t & 63;
    const int fr = l & 15, fq = l >> 4;
    const int wm = (wv & 1) * 32, wn = (wv >> 1) * 32;

    f32x4 acc[2][2];
    #pragma unroll
    for (int mi = 0; mi < 2; ++mi)
        #pragma unroll
        for (int ni = 0; ni < 2; ++ni) {
            f32x4 z = {0.f, 0.f, 0.f, 0.f};
            acc[mi][ni] = z;
        }

    float4 pa[4], pw[4];
    #pragma unroll
    for (int q = 0; q < 4; ++q) {
        pa[q] = aok ? *(const float4*)(asrc + q * 4) : make_float4(0.f, 0.f, 0.f, 0.f);
        pw[q] = *(const float4*)(wsrc + q * 4);
    }

    const int abyte0 = sr * 128 + sc * 2;
    const int asw0   = (abyte0)      ^ ((sr & 7) << 4);
    const int asw1   = (abyte0 + 16) ^ ((sr & 7) << 4);

    for (int kt = 0; kt < 12; ++kt) {
        __syncthreads();
        // stage prefetched regs -> LDS (convert to bf16 hi/lo)
        {
            ushort4 hh[4], ll[4];
            #pragma unroll
            for (int q = 0; q < 4; ++q) {
                hh[q].x = f2bf(pa[q].x); ll[q].x = f2bf(pa[q].x - bf2f(hh[q].x));
                hh[q].y = f2bf(pa[q].y); ll[q].y = f2bf(pa[q].y - bf2f(hh[q].y));
                hh[q].z = f2bf(pa[q].z); ll[q].z = f2bf(pa[q].z - bf2f(hh[q].z));
                hh[q].w = f2bf(pa[q].w); ll[q].w = f2bf(pa[q].w - bf2f(hh[q].w));
            }
            *(ushort4*)(AhB + asw0)     = hh[0];
            *(ushort4*)(AhB + asw0 + 8) = hh[1];
            *(ushort4*)(AhB + asw1)     = hh[2];
            *(ushort4*)(AhB + asw1 + 8) = hh[3];
            *(ushort4*)(AlB + asw0)     = ll[0];
            *(ushort4*)(AlB + asw0 + 8) = ll[1];
            *(ushort4*)(AlB + asw1)     = ll[2];
            *(ushort4*)(AlB + asw1 + 8) = ll[3];
            #pragma unroll
            for (int q = 0; q < 4; ++q) {
                hh[q].x = f2bf(pw[q].x); ll[q].x = f2bf(pw[q].x - bf2f(hh[q].x));
                hh[q].y = f2bf(pw[q].y); ll[q].y = f2bf(pw[q].y - bf2f(hh[q].y));
                hh[q].z = f2bf(pw[q].z); ll[q].z = f2bf(pw[q].z - bf2f(hh[q].z));
                hh[q].w = f2bf(pw[q].w); ll[q].w = f2bf(pw[q].w - bf2f(hh[q].w));
            }
            *(ushort4*)(WhB + asw0)     = hh[0];
            *(ushort4*)(WhB + asw0 + 8) = hh[1];
            *(ushort4*)(WhB + asw1)     = hh[2];
            *(ushort4*)(WhB + asw1 + 8) = hh[3];
            *(ushort4*)(WlB + asw0)     = ll[0];
            *(ushort4*)(WlB + asw0 + 8) = ll[1];
            *(ushort4*)(WlB + asw1)     = ll[2];
            *(ushort4*)(WlB + asw1 + 8) = ll[3];
        }
        __syncthreads();
        // prefetch next K-tile while MFMA runs
        if (kt < 11) {
            const float* an = asrc + (kt + 1) * 64;
            const float* wn2 = wsrc + (kt + 1) * 64;
            #pragma unroll
            for (int q = 0; q < 4; ++q) {
                pa[q] = aok ? *(const float4*)(an + q * 4) : make_float4(0.f, 0.f, 0.f, 0.f);
                pw[q] = *(const float4*)(wn2 + q * 4);
            }
        }
        #pragma unroll
        for (int ks = 0; ks < 2; ++ks) {
            int kb = ks * 64 + fq * 16;
            bf16x8 ah[2], al[2], bh[2], bl[2];
            #pragma unroll
            for (int mi = 0; mi < 2; ++mi) {
                int r    = wm + mi * 16 + fr;
                int byte = (r * 128 + kb) ^ ((r & 7) << 4);
                ah[mi] = *(const bf16x8*)(AhB + byte);
                al[mi] = *(const bf16x8*)(AlB + byte);
            }
            #pragma unroll
            for (int ni = 0; ni < 2; ++ni) {
                int r    = wn + ni * 16 + fr;
                int byte = (r * 128 + kb) ^ ((r & 7) << 4);
                bh[ni] = *(const bf16x8*)(WhB + byte);
                bl[ni] = *(const bf16x8*)(WlB + byte);
            }
            #pragma unroll
            for (int mi = 0; mi < 2; ++mi)
                #pragma unroll
                for (int ni = 0; ni < 2; ++ni) {
                    acc[mi][ni] = __builtin_amdgcn_mfma_f32_16x16x32_bf16(ah[mi], bh[ni], acc[mi][ni], 0, 0, 0);
                    acc[mi][ni] = __builtin_amdgcn_mfma_f32_16x16x32_bf16(ah[mi], bl[ni], acc[mi][ni], 0, 0, 0);
                    acc[mi][ni] = __builtin_amdgcn_mfma_f32_16x16x32_bf16(al[mi], bh[ni], acc[mi][ni], 0, 0, 0);
                }
        }
    }

    // epilogue
    #pragma unroll
    for (int mi = 0; mi < 2; ++mi) {
        #pragma unroll
        for (int j = 0; j < 4; ++j) {
            int m = m0 + wm + mi * 16 + fq * 4 + j;
            if (m < M_) {
                #pragma unroll
                for (int ni = 0; ni < 2; ++ni) {
                    int n = n0 + wn + ni * 16 + fr;
                    C[(size_t)m * N + n] = acc[mi][ni][j] + bias[n];
                }
            }
        }
    }
}

// ---------------------------------------------------------------------------
// Attention: one block per (b,h).  S=17, DH=64.  (unchanged)
// ---------------------------------------------------------------------------
__global__ __launch_bounds__(128)
void attn_kernel(const float* __restrict__ qkv, float* __restrict__ obuf)
{
    __shared__ float qs[S_][65], ks[S_][65], vs[S_][65], att[S_][18];
    const int bh = blockIdx.x, b = bh / H_, h = bh % H_;
    const int bq = b * S_;
    const int tid = threadIdx.x;

    for (int idx = tid; idx < S_ * 64; idx += 128) {
        int s = idx >> 6, d = idx & 63;
        size_t off = (size_t)(bq + s) * (3 * D_) + h * 64 + d;
        qs[s][d] = qkv[off];
        ks[s][d] = qkv[off + D_];
        vs[s][d] = qkv[off + 2 * D_];
    }
    __syncthreads();
    for (int t = tid; t < S_ * S_; t += 128) {
        int i = t / S_, j = t % S_;
        float sdot = 0.f;
        #pragma unroll
        for (int d = 0; d < 64; ++d) sdot = fmaf(qs[i][d], ks[j][d], sdot);
        att[i][j] = sdot * 0.125f;
    }
    __syncthreads();
    if (tid < S_) {
        float mx = -1e30f;
        for (int j = 0; j < S_; ++j) mx = fmaxf(mx, att[tid][j]);
        float ssum = 0.f;
        for (int j = 0; j < S_; ++j) { float e = expf(att[tid][j] - mx); att[tid][j] = e; ssum += e; }
        float inv = 1.0f / ssum;
        for (int j = 0; j < S_; ++j) att[tid][j] *= inv;
    }
    __syncthreads();
    for (int t = tid; t < S_ * 64; t += 128) {
        int i = t >> 6, d = t & 63;
        float s = 0.f;
        #pragma unroll
        for (int j = 0; j < S_; ++j) s = fmaf(att[i][j], vs[j][d], s);
        obuf[(size_t)(bq + i) * D_ + h * 64 + d] = s;
    }
}

// ---------------------------------------------------------------------------
// Residual + LayerNorm (unchanged)
// ---------------------------------------------------------------------------
__global__ __launch_bounds__(256)
void resln_kernel(const float* __restrict__ z0, const float* __restrict__ proj,
                  const float* __restrict__ ln_g, const float* __restrict__ ln_b,
                  float* __restrict__ abuf, float* __restrict__ dout, int writeOut)
{
    const int r = blockIdx.x;
    __shared__ float sm[8];
    float v[3];
    #pragma unroll
    for (int p = 0; p < 3; ++p) {
        int d = threadIdx.x + 256 * p;
        v[p] = z0[(size_t)r * D_ + d] + proj[(size_t)r * D_ + d];
    }
    float sum = 0.f, ss = 0.f;
    #pragma unroll
    for (int p = 0; p < 3; ++p) { sum += v[p]; ss += v[p] * v[p]; }
    #pragma unroll
    for (int o = 32; o; o >>= 1) { sum += __shfl_down(sum, o); ss += __shfl_down(ss, o); }
    int wid = threadIdx.x >> 6, lane = threadIdx.x & 63;
    if (lane == 0) { sm[wid * 2] = sum; sm[wid * 2 + 1] = ss; }
    __syncthreads();
    sum = sm[0] + sm[2] + sm[4] + sm[6];
    ss  = sm[1] + sm[3] + sm[5] + sm[7];
    float m = sum * (1.0f / D_), rstd = rsqrtf(ss * (1.0f / D_) - m * m + 1e-5f);
    #pragma unroll
    for (int p = 0; p < 3; ++p) {
        int d = threadIdx.x + 256 * p;
        float a = (v[p] - m) * rstd * ln_g[d] + ln_b[d];
        abuf[(size_t)r * D_ + d] = a;
        if (writeOut && (r % S_) == 0) dout[(size_t)(r / S_) * D_ + d] = a;
    }
}

// ---------------------------------------------------------------------------
extern "C" void kernel_launch(void* const* d_in, const int* in_sizes, int n_in,
                              void* d_out, int out_size, void* d_ws, size_t ws_size,
                              hipStream_t stream)
{
    const float* x     = (const float*)d_in[0];
    const float* cls   = (const float*)d_in[1];
    const float* ln_g  = (const float*)d_in[2];
    const float* ln_b  = (const float*)d_in[3];
    const float* gln_g = (const float*)d_in[4];
    const float* gln_b = (const float*)d_in[5];
    const float* gW1   = (const float*)d_in[6];
    const float* gb1   = (const float*)d_in[7];
    const float* gW2   = (const float*)d_in[8];
    const float* gb2   = (const float*)d_in[9];
    const float* Wqkv  = (const float*)d_in[10];
    const float* bqkv  = (const float*)d_in[11];
    const float* Wo    = (const float*)d_in[12];
    const float* bo    = (const float*)d_in[13];
    float* out = (float*)d_out;

    float* ws   = (float*)d_ws;
    float* wbuf = ws;                         // 65536
    float* topv = ws + BN_;                   // 256
    int*   topi = (int*)(ws + BN_ + 256);     // 256
    float* z0   = ws + BN_ + 512;
    float* abuf = z0 + (size_t)M_ * D_;
    float* qkvb = abuf + (size_t)M_ * D_;     // M*2304
    float* obuf = qkvb + (size_t)M_ * 3 * D_;
    float* projb = obuf + (size_t)M_ * D_;

    gate_kernel<<<BN_ / 128, 256, 0, stream>>>(x, gln_g, gln_b, gW1, gb1, gW2, gb2, wbuf);
    topk_kernel<<<B_, 1024, 0, stream>>>(wbuf, topv, topi);
    build_kernel<<<M_, 256, 0, stream>>>(x, cls, ln_g, ln_b, topv, topi, z0, abuf);
    for (int l = 0; l < L_; ++l) {
        gemm_mfma<<<dim3(5, 36), 256, 0, stream>>>(abuf, Wqkv + (size_t)l * 3 * D_ * D_,
                                                   bqkv + (size_t)l * 3 * D_, qkvb, 3 * D_);
        attn_kernel<<<B_ * H_, 128, 0, stream>>>(qkvb, obuf);
        gemm_mfma<<<dim3(5, 12), 256, 0, stream>>>(obuf, Wo + (size_t)l * D_ * D_,
                                                   bo + (size_t)l * D_, projb, D_);
        resln_kernel<<<M_, 256, 0, stream>>>(z0, projb, ln_g, ln_b, abuf, out,
                                             (l == L_ - 1) ? 1 : 0);
    }
}

// Round 5
// 180.419 us; speedup vs baseline: 2.0897x; 1.0364x over previous
//
#include <hip/hip_runtime.h>
#include <hip/hip_bf16.h>
#include <hip/hip_cooperative_groups.h>
#include <math.h>

namespace cg = cooperative_groups;

#define B_   16
#define N_   4096
#define D_   768
#define H_   12
#define L_   2
#define K_   16
#define S_   17
#define M_   272          // B_*S_
#define BN_  65536        // B_*N_
#define GRID_ 256

typedef __bf16 bf16x8 __attribute__((ext_vector_type(8)));
typedef float  f32x4  __attribute__((ext_vector_type(4)));

static __device__ __forceinline__ unsigned short f2bf(float f) {
    __bf16 h = (__bf16)f;
    return __builtin_bit_cast(unsigned short, h);
}
static __device__ __forceinline__ float bf2f(unsigned short u) {
    __bf16 h = __builtin_bit_cast(__bf16, u);
    return (float)h;
}
static __device__ __forceinline__ unsigned long long umax64(unsigned long long a, unsigned long long b) {
    return a > b ? a : b;
}

// ===========================================================================
// Stage bodies (shared by the fused cooperative kernel and the fallback path)
// ===========================================================================

// --- gate: 128 instances starting at bn0; smem = 49152B scratch -------------
static __device__ __forceinline__
void gate_block(unsigned short* smem,
                const float* __restrict__ x,  const float* __restrict__ gln_g,
                const float* __restrict__ gln_b, const float* __restrict__ gW1,
                const float* __restrict__ gb1, const float* __restrict__ gW2,
                const float* __restrict__ gb2, float* __restrict__ wbuf,
                int bn0, int t)
{
    char* XhB = (char*)(smem);           // [128][64] bf16 hi, swizzled
    char* XlB = (char*)(smem + 8192);
    char* WhB = (char*)(smem + 16384);   // [64][64]
    char* WlB = (char*)(smem + 20480);

    const int trow  = t >> 1;            // 0..127
    const int thalf = (t & 1) * 32;
    const int te    = t >> 2;            // 0..63
    const int tq    = (t & 3) * 16;

    const float* xrow = x + (size_t)(bn0 + trow) * D_ + thalf;
    const float* wrow = gW1 + (size_t)te * D_ + tq;

    const int wv = t >> 6;
    const int la = t & 63;
    const int fr = la & 15;
    const int fq = la >> 4;

    f32x4 acc[2][4];
    #pragma unroll
    for (int mi = 0; mi < 2; ++mi)
        #pragma unroll
        for (int ni = 0; ni < 4; ++ni) {
            f32x4 z = {0.f, 0.f, 0.f, 0.f};
            acc[mi][ni] = z;
        }

    float sxp = 0.f, sxxp = 0.f;
    float a1p = 0.f, a2p = 0.f;

    for (int kt = 0; kt < 12; ++kt) {
        __syncthreads();
        const float* src = xrow + kt * 64;
        #pragma unroll
        for (int j = 0; j < 8; ++j) {
            float4 v = *(const float4*)(src + j * 4);
            sxp  += v.x + v.y + v.z + v.w;
            sxxp += v.x * v.x + v.y * v.y + v.z * v.z + v.w * v.w;
            ushort4 hh, ll;
            hh.x = f2bf(v.x); ll.x = f2bf(v.x - bf2f(hh.x));
            hh.y = f2bf(v.y); ll.y = f2bf(v.y - bf2f(hh.y));
            hh.z = f2bf(v.z); ll.z = f2bf(v.z - bf2f(hh.z));
            hh.w = f2bf(v.w); ll.w = f2bf(v.w - bf2f(hh.w));
            int byte = trow * 128 + (thalf + j * 4) * 2;
            int sw   = byte ^ ((trow & 7) << 4);
            *(ushort4*)(XhB + sw) = hh;
            *(ushort4*)(XlB + sw) = ll;
        }
        const float* wsrc = wrow + kt * 64;
        const float* gsrc = gln_g + kt * 64 + tq;
        const float* bsrc = gln_b + kt * 64 + tq;
        #pragma unroll
        for (int j = 0; j < 4; ++j) {
            float4 w4 = *(const float4*)(wsrc + j * 4);
            float4 g4 = *(const float4*)(gsrc + j * 4);
            float4 b4 = *(const float4*)(bsrc + j * 4);
            float4 wt;
            wt.x = w4.x * g4.x; wt.y = w4.y * g4.y;
            wt.z = w4.z * g4.z; wt.w = w4.w * g4.w;
            a1p += wt.x + wt.y + wt.z + wt.w;
            a2p += b4.x * w4.x + b4.y * w4.y + b4.z * w4.z + b4.w * w4.w;
            ushort4 hh, ll;
            hh.x = f2bf(wt.x); ll.x = f2bf(wt.x - bf2f(hh.x));
            hh.y = f2bf(wt.y); ll.y = f2bf(wt.y - bf2f(hh.y));
            hh.z = f2bf(wt.z); ll.z = f2bf(wt.z - bf2f(hh.z));
            hh.w = f2bf(wt.w); ll.w = f2bf(wt.w - bf2f(hh.w));
            int byte = te * 128 + (tq + j * 4) * 2;
            int sw   = byte ^ ((te & 7) << 4);
            *(ushort4*)(WhB + sw) = hh;
            *(ushort4*)(WlB + sw) = ll;
        }
        __syncthreads();
        #pragma unroll
        for (int ks = 0; ks < 2; ++ks) {
            int k0 = ks * 32 + fq * 8;
            bf16x8 ah[2], al[2], bh[4], bl[4];
            #pragma unroll
            for (int mi = 0; mi < 2; ++mi) {
                int r    = wv * 32 + mi * 16 + fr;
                int byte = (r * 128 + k0 * 2) ^ ((r & 7) << 4);
                ah[mi] = *(const bf16x8*)(XhB + byte);
                al[mi] = *(const bf16x8*)(XlB + byte);
            }
            #pragma unroll
            for (int ni = 0; ni < 4; ++ni) {
                int e    = ni * 16 + fr;
                int byte = (e * 128 + k0 * 2) ^ ((e & 7) << 4);
                bh[ni] = *(const bf16x8*)(WhB + byte);
                bl[ni] = *(const bf16x8*)(WlB + byte);
            }
            #pragma unroll
            for (int mi = 0; mi < 2; ++mi)
                #pragma unroll
                for (int ni = 0; ni < 4; ++ni) {
                    acc[mi][ni] = __builtin_amdgcn_mfma_f32_16x16x32_bf16(ah[mi], bh[ni], acc[mi][ni], 0, 0, 0);
                    acc[mi][ni] = __builtin_amdgcn_mfma_f32_16x16x32_bf16(ah[mi], bl[ni], acc[mi][ni], 0, 0, 0);
                    acc[mi][ni] = __builtin_amdgcn_mfma_f32_16x16x32_bf16(al[mi], bh[ni], acc[mi][ni], 0, 0, 0);
                }
        }
    }
    __syncthreads();

    float* F    = (float*)smem;
    float* mS   = F;          // 128
    float* rS   = F + 128;    // 128
    float* A1s  = F + 256;    // 64
    float* A2s  = F + 320;    // 64
    float* redS = F + 384;    // [128][2]
    float* redQ = F + 640;    // [128][2]
    float* rA1  = F + 896;    // [64][4]
    float* rA2  = F + 1152;   // [64][4]

    redS[trow * 2 + (t & 1)] = sxp;
    redQ[trow * 2 + (t & 1)] = sxxp;
    rA1[te * 4 + (t & 3)] = a1p;
    rA2[te * 4 + (t & 3)] = a2p;
    __syncthreads();
    if (t < 128) {
        float s = redS[t * 2] + redS[t * 2 + 1];
        float q = redQ[t * 2] + redQ[t * 2 + 1];
        float m = s * (1.0f / D_);
        mS[t] = m;
        rS[t] = rsqrtf(q * (1.0f / D_) - m * m + 1e-5f);
    }
    if (t < 64) {
        A1s[t] = rA1[t * 4] + rA1[t * 4 + 1] + rA1[t * 4 + 2] + rA1[t * 4 + 3];
        A2s[t] = rA2[t * 4] + rA2[t * 4 + 1] + rA2[t * 4 + 2] + rA2[t * 4 + 3];
    }
    __syncthreads();

    float w2v[4], a1v[4], a2b[4];
    #pragma unroll
    for (int ni = 0; ni < 4; ++ni) {
        int e = ni * 16 + fr;
        w2v[ni] = gW2[e];
        a1v[ni] = A1s[e];
        a2b[ni] = A2s[e] + gb1[e];
    }
    float gb2v = gb2[0];

    #pragma unroll
    for (int mi = 0; mi < 2; ++mi) {
        #pragma unroll
        for (int j = 0; j < 4; ++j) {
            int inst = wv * 32 + mi * 16 + fq * 4 + j;
            float m = mS[inst], rs = rS[inst];
            float tp = 0.f;
            #pragma unroll
            for (int ni = 0; ni < 4; ++ni) {
                float h  = rs * (acc[mi][ni][j] - m * a1v[ni]) + a2b[ni];
                float hg = 0.5f * h * (1.0f + erff(h * 0.70710678118654752f));
                tp = fmaf(hg, w2v[ni], tp);
            }
            tp += __shfl_xor(tp, 1);
            tp += __shfl_xor(tp, 2);
            tp += __shfl_xor(tp, 4);
            tp += __shfl_xor(tp, 8);
            if (fr == 0) wbuf[bn0 + inst] = 1.0f / (1.0f + expf(-(tp + gb2v)));
        }
    }
}

// --- top-16 for one bag (256 threads) ---------------------------------------
static __device__ __forceinline__
void topk_block(unsigned long long* SB, const float* __restrict__ wbuf,
                float* __restrict__ topv, int* __restrict__ topi, int b, int t)
{
    unsigned long long* wred   = SB;       // [4]
    unsigned long long* winkey = SB + 8;
    const int la = t & 63, wid = t >> 6;

    unsigned long long key[16];
    #pragma unroll
    for (int j = 0; j < 16; ++j) {
        int i = t + 256 * j;
        float v = wbuf[(size_t)b * N_ + i];
        key[j] = ((unsigned long long)__float_as_uint(v) << 12) | (unsigned long long)(4095 - i);
    }
    for (int k = 0; k < K_; ++k) {
        unsigned long long kk = key[0];
        #pragma unroll
        for (int j = 1; j < 16; ++j) kk = umax64(kk, key[j]);
        #pragma unroll
        for (int o = 1; o < 64; o <<= 1) kk = umax64(kk, (unsigned long long)__shfl_xor(kk, o));
        if (la == 0) wred[wid] = kk;
        __syncthreads();
        if (t == 0) {
            unsigned long long m = umax64(umax64(wred[0], wred[1]), umax64(wred[2], wred[3]));
            *winkey = m;
            int wi = 4095 - (int)(m & 0xfffULL);
            topv[b * K_ + k] = __uint_as_float((unsigned int)(m >> 12));
            topi[b * K_ + k] = wi;
        }
        __syncthreads();
        unsigned long long m = *winkey;
        int wi = 4095 - (int)(m & 0xfffULL);
        #pragma unroll
        for (int j = 0; j < 16; ++j)
            if (wi == t + 256 * j) key[j] = 0ULL;
        __syncthreads();
    }
}

// --- build one seq row r: gather+weight, LN -> z0, abuf ---------------------
static __device__ __forceinline__
void build_row(float* sm, const float* __restrict__ x, const float* __restrict__ cls,
               const float* __restrict__ ln_g, const float* __restrict__ ln_b,
               const float* __restrict__ topv, const int* __restrict__ topi,
               float* __restrict__ z0, float* __restrict__ abuf, int r, int t)
{
    const int b = r / S_, s = r % S_;
    float v[3];
    if (s == 0) {
        #pragma unroll
        for (int p = 0; p < 3; ++p) v[p] = cls[t + 256 * p];
    } else {
        int   idx = topi[b * K_ + s - 1];
        float tv  = topv[b * K_ + s - 1];
        const float* row = &x[((size_t)b * N_ + idx) * D_];
        #pragma unroll
        for (int p = 0; p < 3; ++p) v[p] = row[t + 256 * p] * tv;
    }
    float sum = 0.f, ss = 0.f;
    #pragma unroll
    for (int p = 0; p < 3; ++p) { sum += v[p]; ss += v[p] * v[p]; }
    #pragma unroll
    for (int o = 32; o; o >>= 1) { sum += __shfl_down(sum, o); ss += __shfl_down(ss, o); }
    int wid = t >> 6, la = t & 63;
    if (la == 0) { sm[wid * 2] = sum; sm[wid * 2 + 1] = ss; }
    __syncthreads();
    sum = sm[0] + sm[2] + sm[4] + sm[6];
    ss  = sm[1] + sm[3] + sm[5] + sm[7];
    __syncthreads();
    float m = sum * (1.0f / D_), rstd = rsqrtf(ss * (1.0f / D_) - m * m + 1e-5f);
    #pragma unroll
    for (int p = 0; p < 3; ++p) {
        int d = t + 256 * p;
        float z = (v[p] - m) * rstd * ln_g[d] + ln_b[d];
        z0[(size_t)r * D_ + d]   = z;
        abuf[(size_t)r * D_ + d] = z;
    }
}

// --- MFMA GEMM tile (bf16-split 3-pass), 64x64, BK=64 -----------------------
static __device__ __forceinline__
void gemm_stage(char* SB, const float* __restrict__ A, const float* __restrict__ W,
                const float* __restrict__ bias, float* __restrict__ C, int N,
                int m0, int n0, int t)
{
    char* AhB = SB;
    char* AlB = SB + 8192;
    char* WhB = SB + 16384;
    char* WlB = SB + 24576;

    const int sr = t >> 2;
    const int sc = (t & 3) * 16;
    const int gm = m0 + sr;
    const bool aok = (gm < M_);
    const float* asrc = A + (size_t)gm * D_ + sc;
    const float* wsrc = W + (size_t)(n0 + sr) * D_ + sc;

    const int wv = t >> 6, la = t & 63;
    const int fr = la & 15, fq = la >> 4;
    const int wm = (wv & 1) * 32, wn = (wv >> 1) * 32;

    f32x4 acc[2][2];
    #pragma unroll
    for (int mi = 0; mi < 2; ++mi)
        #pragma unroll
        for (int ni = 0; ni < 2; ++ni) {
            f32x4 z = {0.f, 0.f, 0.f, 0.f};
            acc[mi][ni] = z;
        }

    float4 pa[4], pw[4];
    #pragma unroll
    for (int q = 0; q < 4; ++q) {
        pa[q] = aok ? *(const float4*)(asrc + q * 4) : make_float4(0.f, 0.f, 0.f, 0.f);
        pw[q] = *(const float4*)(wsrc + q * 4);
    }

    const int abyte0 = sr * 128 + sc * 2;
    const int asw0   = (abyte0)      ^ ((sr & 7) << 4);
    const int asw1   = (abyte0 + 16) ^ ((sr & 7) << 4);

    for (int kt = 0; kt < 12; ++kt) {
        __syncthreads();
        {
            ushort4 hh[4], ll[4];
            #pragma unroll
            for (int q = 0; q < 4; ++q) {
                hh[q].x = f2bf(pa[q].x); ll[q].x = f2bf(pa[q].x - bf2f(hh[q].x));
                hh[q].y = f2bf(pa[q].y); ll[q].y = f2bf(pa[q].y - bf2f(hh[q].y));
                hh[q].z = f2bf(pa[q].z); ll[q].z = f2bf(pa[q].z - bf2f(hh[q].z));
                hh[q].w = f2bf(pa[q].w); ll[q].w = f2bf(pa[q].w - bf2f(hh[q].w));
            }
            *(ushort4*)(AhB + asw0)     = hh[0];
            *(ushort4*)(AhB + asw0 + 8) = hh[1];
            *(ushort4*)(AhB + asw1)     = hh[2];
            *(ushort4*)(AhB + asw1 + 8) = hh[3];
            *(ushort4*)(AlB + asw0)     = ll[0];
            *(ushort4*)(AlB + asw0 + 8) = ll[1];
            *(ushort4*)(AlB + asw1)     = ll[2];
            *(ushort4*)(AlB + asw1 + 8) = ll[3];
            #pragma unroll
            for (int q = 0; q < 4; ++q) {
                hh[q].x = f2bf(pw[q].x); ll[q].x = f2bf(pw[q].x - bf2f(hh[q].x));
                hh[q].y = f2bf(pw[q].y); ll[q].y = f2bf(pw[q].y - bf2f(hh[q].y));
                hh[q].z = f2bf(pw[q].z); ll[q].z = f2bf(pw[q].z - bf2f(hh[q].z));
                hh[q].w = f2bf(pw[q].w); ll[q].w = f2bf(pw[q].w - bf2f(hh[q].w));
            }
            *(ushort4*)(WhB + asw0)     = hh[0];
            *(ushort4*)(WhB + asw0 + 8) = hh[1];
            *(ushort4*)(WhB + asw1)     = hh[2];
            *(ushort4*)(WhB + asw1 + 8) = hh[3];
            *(ushort4*)(WlB + asw0)     = ll[0];
            *(ushort4*)(WlB + asw0 + 8) = ll[1];
            *(ushort4*)(WlB + asw1)     = ll[2];
            *(ushort4*)(WlB + asw1 + 8) = ll[3];
        }
        __syncthreads();
        if (kt < 11) {
            const float* an  = asrc + (kt + 1) * 64;
            const float* wn2 = wsrc + (kt + 1) * 64;
            #pragma unroll
            for (int q = 0; q < 4; ++q) {
                pa[q] = aok ? *(const float4*)(an + q * 4) : make_float4(0.f, 0.f, 0.f, 0.f);
                pw[q] = *(const float4*)(wn2 + q * 4);
            }
        }
        #pragma unroll
        for (int ks = 0; ks < 2; ++ks) {
            int kb = ks * 64 + fq * 16;
            bf16x8 ah[2], al[2], bh[2], bl[2];
            #pragma unroll
            for (int mi = 0; mi < 2; ++mi) {
                int r    = wm + mi * 16 + fr;
                int byte = (r * 128 + kb) ^ ((r & 7) << 4);
                ah[mi] = *(const bf16x8*)(AhB + byte);
                al[mi] = *(const bf16x8*)(AlB + byte);
            }
            #pragma unroll
            for (int ni = 0; ni < 2; ++ni) {
                int r    = wn + ni * 16 + fr;
                int byte = (r * 128 + kb) ^ ((r & 7) << 4);
                bh[ni] = *(const bf16x8*)(WhB + byte);
                bl[ni] = *(const bf16x8*)(WlB + byte);
            }
            #pragma unroll
            for (int mi = 0; mi < 2; ++mi)
                #pragma unroll
                for (int ni = 0; ni < 2; ++ni) {
                    acc[mi][ni] = __builtin_amdgcn_mfma_f32_16x16x32_bf16(ah[mi], bh[ni], acc[mi][ni], 0, 0, 0);
                    acc[mi][ni] = __builtin_amdgcn_mfma_f32_16x16x32_bf16(ah[mi], bl[ni], acc[mi][ni], 0, 0, 0);
                    acc[mi][ni] = __builtin_amdgcn_mfma_f32_16x16x32_bf16(al[mi], bh[ni], acc[mi][ni], 0, 0, 0);
                }
        }
    }

    #pragma unroll
    for (int mi = 0; mi < 2; ++mi) {
        #pragma unroll
        for (int j = 0; j < 4; ++j) {
            int m = m0 + wm + mi * 16 + fq * 4 + j;
            if (m < M_) {
                #pragma unroll
                for (int ni = 0; ni < 2; ++ni) {
                    int n = n0 + wn + ni * 16 + fr;
                    C[(size_t)m * N + n] = acc[mi][ni][j] + bias[n];
                }
            }
        }
    }
}

// --- attention for one (b,h), 256 threads -----------------------------------
static __device__ __forceinline__
void attn_block(float* F, const float* __restrict__ qkvb, float* __restrict__ obuf,
                int bh, int t)
{
    float* qs  = F;                 // [17][65]
    float* ks  = F + S_ * 65;
    float* vs  = F + 2 * S_ * 65;
    float* att = F + 3 * S_ * 65;   // [17][18]
    const int b = bh / H_, h = bh % H_;
    const int bq = b * S_;
    for (int idx = t; idx < S_ * 64; idx += 256) {
        int s = idx >> 6, d = idx & 63;
        size_t off = (size_t)(bq + s) * (3 * D_) + h * 64 + d;
        qs[s * 65 + d] = qkvb[off];
        ks[s * 65 + d] = qkvb[off + D_];
        vs[s * 65 + d] = qkvb[off + 2 * D_];
    }
    __syncthreads();
    for (int idx = t; idx < S_ * S_; idx += 256) {
        int i = idx / S_, j = idx % S_;
        float sdot = 0.f;
        #pragma unroll
        for (int d = 0; d < 64; ++d) sdot = fmaf(qs[i * 65 + d], ks[j * 65 + d], sdot);
        att[i * 18 + j] = sdot * 0.125f;
    }
    __syncthreads();
    if (t < S_) {
        float mx = -1e30f;
        for (int j = 0; j < S_; ++j) mx = fmaxf(mx, att[t * 18 + j]);
        float ssum = 0.f;
        for (int j = 0; j < S_; ++j) { float e = expf(att[t * 18 + j] - mx); att[t * 18 + j] = e; ssum += e; }
        float inv = 1.0f / ssum;
        for (int j = 0; j < S_; ++j) att[t * 18 + j] *= inv;
    }
    __syncthreads();
    for (int idx = t; idx < S_ * 64; idx += 256) {
        int i = idx >> 6, d = idx & 63;
        float s = 0.f;
        #pragma unroll
        for (int j = 0; j < S_; ++j) s = fmaf(att[i * 18 + j], vs[j * 65 + d], s);
        obuf[(size_t)(bq + i) * D_ + h * 64 + d] = s;
    }
}

// --- residual + LN for one row r --------------------------------------------
static __device__ __forceinline__
void resln_row(float* sm, const float* __restrict__ z0, const float* __restrict__ projb,
               const float* __restrict__ ln_g, const float* __restrict__ ln_b,
               float* __restrict__ abuf, float* __restrict__ out, int r, int t, int writeOut)
{
    float v[3];
    #pragma unroll
    for (int p = 0; p < 3; ++p) {
        int d = t + 256 * p;
        v[p] = z0[(size_t)r * D_ + d] + projb[(size_t)r * D_ + d];
    }
    float sum = 0.f, ss = 0.f;
    #pragma unroll
    for (int p = 0; p < 3; ++p) { sum += v[p]; ss += v[p] * v[p]; }
    #pragma unroll
    for (int o = 32; o; o >>= 1) { sum += __shfl_down(sum, o); ss += __shfl_down(ss, o); }
    int wid = t >> 6, la = t & 63;
    if (la == 0) { sm[wid * 2] = sum; sm[wid * 2 + 1] = ss; }
    __syncthreads();
    sum = sm[0] + sm[2] + sm[4] + sm[6];
    ss  = sm[1] + sm[3] + sm[5] + sm[7];
    __syncthreads();
    float m = sum * (1.0f / D_), rstd = rsqrtf(ss * (1.0f / D_) - m * m + 1e-5f);
    #pragma unroll
    for (int p = 0; p < 3; ++p) {
        int d = t + 256 * p;
        float a = (v[p] - m) * rstd * ln_g[d] + ln_b[d];
        abuf[(size_t)r * D_ + d] = a;
        if (writeOut && (r % S_) == 0) out[(size_t)(r / S_) * D_ + d] = a;
    }
}

// ===========================================================================
// Cooperative mega-kernel (grid = 256 blocks x 256 threads)
// ===========================================================================
__global__ __launch_bounds__(256)
void fused_kernel(const float* __restrict__ x, const float* __restrict__ cls,
                  const float* __restrict__ ln_g, const float* __restrict__ ln_b,
                  const float* __restrict__ gln_g, const float* __restrict__ gln_b,
                  const float* __restrict__ gW1, const float* __restrict__ gb1,
                  const float* __restrict__ gW2, const float* __restrict__ gb2,
                  const float* __restrict__ Wqkv, const float* __restrict__ bqkv,
                  const float* __restrict__ Wo, const float* __restrict__ bo,
                  float* out,
                  float* wbuf, float* topv, int* topi,
                  float* z0, float* abuf, float* qkvb, float* obuf, float* projb)
{
    cg::grid_group grid = cg::this_grid();
    __shared__ __align__(16) char SMEM[49152];
    const int bid = blockIdx.x;
    const int t   = threadIdx.x;

    // stage 0: gate — each block does 2x128 instances
    #pragma unroll 1
    for (int half = 0; half < 2; ++half)
        gate_block((unsigned short*)SMEM, x, gln_g, gln_b, gW1, gb1, gW2, gb2,
                   wbuf, bid * 256 + half * 128, t);
    grid.sync();

    // stage 1: topk
    if (bid < B_) topk_block((unsigned long long*)SMEM, wbuf, topv, topi, bid, t);
    grid.sync();

    // stage 2: build rows (grid-stride over 272)
    #pragma unroll 1
    for (int r = bid; r < M_; r += GRID_)
        build_row((float*)SMEM, x, cls, ln_g, ln_b, topv, topi, z0, abuf, r, t);
    grid.sync();

    // transformer layers
    #pragma unroll 1
    for (int l = 0; l < L_; ++l) {
        if (bid < 180)
            gemm_stage(SMEM, abuf, Wqkv + (size_t)l * 3 * D_ * D_,
                       bqkv + (size_t)l * 3 * D_, qkvb, 3 * D_,
                       (bid / 36) * 64, (bid % 36) * 64, t);
        grid.sync();

        if (bid < B_ * H_) attn_block((float*)SMEM, qkvb, obuf, bid, t);
        grid.sync();

        if (bid < 60)
            gemm_stage(SMEM, obuf, Wo + (size_t)l * D_ * D_,
                       bo + (size_t)l * D_, projb, D_,
                       (bid / 12) * 64, (bid % 12) * 64, t);
        grid.sync();

        #pragma unroll 1
        for (int r = bid; r < M_; r += GRID_)
            resln_row((float*)SMEM, z0, projb, ln_g, ln_b, abuf, out, r, t,
                      (l == L_ - 1) ? 1 : 0);
        if (l == 0) grid.sync();
    }
}

// ===========================================================================
// Fallback standalone kernels (round-3 structure, known good)
// ===========================================================================
__global__ __launch_bounds__(256)
void gate_kernel(const float* __restrict__ x, const float* __restrict__ gln_g,
                 const float* __restrict__ gln_b, const float* __restrict__ gW1,
                 const float* __restrict__ gb1, const float* __restrict__ gW2,
                 const float* __restrict__ gb2, float* __restrict__ wbuf)
{
    __shared__ __align__(16) unsigned short smem[24576];
    gate_block(smem, x, gln_g, gln_b, gW1, gb1, gW2, gb2, wbuf,
               blockIdx.x * 128, threadIdx.x);
}

__global__ __launch_bounds__(256)
void topk_kernel(const float* __restrict__ wbuf, float* __restrict__ topv,
                 int* __restrict__ topi)
{
    __shared__ unsigned long long SB[16];
    topk_block(SB, wbuf, topv, topi, blockIdx.x, threadIdx.x);
}

__global__ __launch_bounds__(256)
void build_kernel(const float* __restrict__ x, const float* __restrict__ cls,
                  const float* __restrict__ ln_g, const float* __restrict__ ln_b,
                  const float* __restrict__ topv, const int* __restrict__ topi,
                  float* __restrict__ z0, float* __restrict__ abuf)
{
    __shared__ float sm[8];
    build_row(sm, x, cls, ln_g, ln_b, topv, topi, z0, abuf, blockIdx.x, threadIdx.x);
}

__global__ __launch_bounds__(256)
void gemm_mfma(const float* __restrict__ A, const float* __restrict__ W,
               const float* __restrict__ bias, float* __restrict__ C, int N)
{
    __shared__ __align__(16) char SB[32768];
    gemm_stage(SB, A, W, bias, C, N, blockIdx.x * 64, blockIdx.y * 64, threadIdx.x);
}

__global__ __launch_bounds__(256)
void attn_kernel(const float* __restrict__ qkvb, float* __restrict__ obuf)
{
    __shared__ __align__(16) float F[3 * S_ * 65 + S_ * 18];
    attn_block(F, qkvb, obuf, blockIdx.x, threadIdx.x);
}

__global__ __launch_bounds__(256)
void resln_kernel(const float* __restrict__ z0, const float* __restrict__ projb,
                  const float* __restrict__ ln_g, const float* __restrict__ ln_b,
                  float* __restrict__ abuf, float* __restrict__ out, int writeOut)
{
    __shared__ float sm[8];
    resln_row(sm, z0, projb, ln_g, ln_b, abuf, out, blockIdx.x, threadIdx.x, writeOut);
}

// ---------------------------------------------------------------------------
extern "C" void kernel_launch(void* const* d_in, const int* in_sizes, int n_in,
                              void* d_out, int out_size, void* d_ws, size_t ws_size,
                              hipStream_t stream)
{
    const float* x     = (const float*)d_in[0];
    const float* cls   = (const float*)d_in[1];
    const float* ln_g  = (const float*)d_in[2];
    const float* ln_b  = (const float*)d_in[3];
    const float* gln_g = (const float*)d_in[4];
    const float* gln_b = (const float*)d_in[5];
    const float* gW1   = (const float*)d_in[6];
    const float* gb1   = (const float*)d_in[7];
    const float* gW2   = (const float*)d_in[8];
    const float* gb2   = (const float*)d_in[9];
    const float* Wqkv  = (const float*)d_in[10];
    const float* bqkv  = (const float*)d_in[11];
    const float* Wo    = (const float*)d_in[12];
    const float* bo    = (const float*)d_in[13];
    float* out = (float*)d_out;

    float* ws   = (float*)d_ws;
    float* wbuf = ws;                         // 65536
    float* topv = ws + BN_;                   // 256
    int*   topi = (int*)(ws + BN_ + 256);     // 256
    float* z0   = ws + BN_ + 512;
    float* abuf = z0 + (size_t)M_ * D_;
    float* qkvb = abuf + (size_t)M_ * D_;     // M*2304
    float* obuf = qkvb + (size_t)M_ * 3 * D_;
    float* projb = obuf + (size_t)M_ * D_;

    // Try the cooperative mega-kernel; fall back to the multi-kernel path on
    // any launch refusal (deterministic per device/driver).
    hipError_t lerr = hipErrorUnknown;
    int nb = 0;
    if (hipOccupancyMaxActiveBlocksPerMultiprocessor(
            &nb, (const void*)fused_kernel, 256, 0) == hipSuccess && nb >= 1) {
        void* args[] = {
            (void*)&x, (void*)&cls, (void*)&ln_g, (void*)&ln_b,
            (void*)&gln_g, (void*)&gln_b, (void*)&gW1, (void*)&gb1,
            (void*)&gW2, (void*)&gb2, (void*)&Wqkv, (void*)&bqkv,
            (void*)&Wo, (void*)&bo, (void*)&out,
            (void*)&wbuf, (void*)&topv, (void*)&topi,
            (void*)&z0, (void*)&abuf, (void*)&qkvb, (void*)&obuf, (void*)&projb
        };
        lerr = hipLaunchCooperativeKernel((const void*)fused_kernel, dim3(GRID_),
                                          dim3(256), args, 0, stream);
    }
    if (lerr != hipSuccess) {
        gate_kernel<<<BN_ / 128, 256, 0, stream>>>(x, gln_g, gln_b, gW1, gb1, gW2, gb2, wbuf);
        topk_kernel<<<B_, 256, 0, stream>>>(wbuf, topv, topi);
        build_kernel<<<M_, 256, 0, stream>>>(x, cls, ln_g, ln_b, topv, topi, z0, abuf);
        for (int l = 0; l < L_; ++l) {
            gemm_mfma<<<dim3(5, 36), 256, 0, stream>>>(abuf, Wqkv + (size_t)l * 3 * D_ * D_,
                                                       bqkv + (size_t)l * 3 * D_, qkvb, 3 * D_);
            attn_kernel<<<B_ * H_, 256, 0, stream>>>(qkvb, obuf);
            gemm_mfma<<<dim3(5, 12), 256, 0, stream>>>(obuf, Wo + (size_t)l * D_ * D_,
                                                       bo + (size_t)l * D_, projb, D_);
            resln_kernel<<<M_, 256, 0, stream>>>(z0, projb, ln_g, ln_b, abuf, out,
                                                 (l == L_ - 1) ? 1 : 0);
        }
    }
}